// Round 7
// baseline (748.379 us; speedup 1.0000x reference)
//
#include <hip/hip_runtime.h>

// MANNet forward, MI355X gfx950. Inputs fp32 (+int32 ids), output fp32.
// R16: k_score split + kc-outer restructure. R12-R15 evidence: any schedule
// needing >~90 loop-invariant VGPRs (afr fragments) gets silently demoted by the
// compiler to per-iteration LDS re-reads (VGPR=56/64/92 across variants, all
// ~170-200us, insensitive to occupancy/VALU/launch-bounds). Fix: kc-outer loop —
// per d-chunk load 4 afr + 4 bf TRANSIENT fragments, 16 MFMAs into acc[4][4]
// (the accumulator is the only long-lived state; compiler always keeps it).
// Every LDS/X fragment read exactly once per block by construction.
// Also: k_score split into k_scmm (y=0..3) and k_sccmb (cmb) dispatches for
// per-path rocprof attribution.

#define DEV static __device__ __forceinline__
#define BAR_LGKM() __asm__ volatile("s_waitcnt lgkmcnt(0)\ns_barrier" ::: "memory")

typedef __attribute__((ext_vector_type(4))) float f32x4;
typedef __attribute__((ext_vector_type(8))) short s16x8;
typedef __attribute__((ext_vector_type(4))) unsigned int u32x4;

constexpr int T = 256, E = 300, EP = 320, H = 128, H2 = 256, H3 = 384, H12 = 1536;
constexpr int M = 1024;            // B*T
constexpr int STY = 262144;        // 4*T*T elements per score type

DEV float b2f(unsigned short h) { return __uint_as_float(((unsigned)h) << 16); }
DEV unsigned short f2b(float f) {
  unsigned u = __float_as_uint(f);
  u += 0x7fff + ((u >> 16) & 1);            // RNE
  return (unsigned short)(u >> 16);
}
DEV unsigned cvt_pk_bf16(float lo, float hi) {   // dst = {bf16(lo), bf16(hi)} RNE
  unsigned r;
  __asm__("v_cvt_pk_bf16_f32 %0, %1, %2" : "=v"(r) : "v"(lo), "v"(hi));
  return r;
}
DEV float rcp_f(float x) {                       // v_rcp_f32: 1 ulp, 1 trans op
  float r;
  __asm__("v_rcp_f32 %0, %1" : "=v"(r) : "v"(x));
  return r;
}
DEV float sigm(float x) { return rcp_f(1.f + __expf(-x)); }
DEV float tanh_f(float x) {
  float e = __expf(2.f * x);
  return __builtin_fmaf(-2.f, rcp_f(e + 1.f), 1.f);
}

DEV s16x8 ldfrag(const unsigned short* p) {
  u32x4 v = *(const u32x4*)p;
  return __builtin_bit_cast(s16x8, v);
}
DEV f32x4 mfma16(s16x8 a, s16x8 b, f32x4 c) {
  return __builtin_amdgcn_mfma_f32_16x16x32_bf16(a, b, c, 0, 0, 0);
}

// ---------------- fused staging: 9x cvt + embed + padw ----------------

struct StageArgs {
  const float* cs[9]; unsigned short* cd[9]; int cn[9];
  const int* idx; const float* emb; unsigned short* xhi; unsigned short* xlo;
  const float* lW; const float* rW; unsigned short* wpad;
};

__global__ void k_stage(StageArgs sa) {
  int seg = blockIdx.y;
  int i = blockIdx.x * 256 + threadIdx.x;
  if (seg < 9) {
    if (i < sa.cn[seg]) sa.cd[seg][i] = f2b(sa.cs[seg][i]);
    return;
  }
  if (seg == 9) {
    if (i >= M * EP) return;
    int m = i / EP, e = i - m * EP;
    int r = sa.idx[m];
    float v = (e < E) ? sa.emb[(size_t)r * E + e] : 0.f;
    unsigned short hi = f2b(v);
    sa.xhi[i] = hi;
    sa.xlo[i] = f2b(v - b2f(hi));
    return;
  }
  if (i >= 4 * H3 * EP) return;
  int e = i % EP, n = (i / EP) % H3, uu = i / (EP * H3);
  const float* src = (uu < 2 ? sa.lW : sa.rW) + (size_t)((uu & 1) * H3 + n) * E;
  sa.wpad[i] = (e < E) ? f2b(src[e]) : (unsigned short)0;
}

// ---------------- generic GEMM: C = (Ahi+Alo) @ W^T (+bias), fp32 out ----------
// tr=1: write transposed C_t[n*M + m] (for j-streamed consumers).

struct GemmDesc {
  const unsigned short* Ahi; const unsigned short* Alo; const unsigned short* W;
  const float* bias; float* Cf; int N; int K; int tr;
};
struct GemmBatch { GemmDesc d[8]; };

__global__ __launch_bounds__(256) void k_gemm(GemmBatch gb) {
  GemmDesc g = gb.d[blockIdx.z];
  int nb = blockIdx.y * 64;
  if (nb >= g.N) return;
  int mb = blockIdx.x * 64;
  int lane = threadIdx.x & 63, w = threadIdx.x >> 6, quad = lane >> 4, l16 = lane & 15;
  int K = g.K;
  const unsigned short* Ahp = g.Ahi + (size_t)(mb + w * 16 + l16) * K + quad * 8;
  const unsigned short* Alp = g.Alo + (size_t)(mb + w * 16 + l16) * K + quad * 8;
  const unsigned short* Wp = g.W + (size_t)(nb + l16) * K + quad * 8;
  f32x4 acc[4];
  #pragma unroll
  for (int nt = 0; nt < 4; ++nt) acc[nt] = f32x4{0.f, 0.f, 0.f, 0.f};
  for (int k = 0; k < K; k += 32) {
    s16x8 ah = ldfrag(Ahp + k);
    s16x8 al = ldfrag(Alp + k);
    #pragma unroll
    for (int nt = 0; nt < 4; ++nt) {
      s16x8 b = ldfrag(Wp + (size_t)nt * 16 * K + k);
      acc[nt] = mfma16(ah, b, acc[nt]);
      acc[nt] = mfma16(al, b, acc[nt]);
    }
  }
  int mr0 = mb + w * 16 + quad * 4;
  #pragma unroll
  for (int nt = 0; nt < 4; ++nt) {
    int col = nb + nt * 16 + l16;
    float bv = g.bias ? g.bias[col] : 0.f;
    #pragma unroll
    for (int r = 0; r < 4; ++r) {
      if (g.tr)
        g.Cf[(size_t)col * M + (mr0 + r)] = acc[nt][r] + bv;
      else
        g.Cf[(size_t)(mr0 + r) * g.N + col] = acc[nt][r] + bv;
    }
  }
}

// ---------------- GRU recurrence v5: 512 thr, in-register hi/lo combine --------

struct RecArgs {
  const unsigned short* whh[4];
  const float* pre[4];
  float* outf[4];
  unsigned short* outhi[4];
  unsigned short* outlo[4];
  unsigned short* agghi[4];      // null -> no agg copy
  unsigned short* agglo[4];
  const float* bhh[4];
  int colOff[4];
  int dir[4];
};

__global__ __launch_bounds__(512) void k_gru(RecArgs ra) {
  int u = blockIdx.x;
  __shared__ __align__(16) unsigned short hs[2][16 * 136];
  int tid = threadIdx.x, lane = tid & 63, w8 = tid >> 6;
  int quad = lane >> 4, l16 = lane & 15;
  for (int i = tid; i < 2 * 16 * 136; i += 512) ((unsigned short*)hs)[i] = 0;
  const unsigned short* whh = ra.whh[u];
  s16x8 bq[3][4];
  #pragma unroll
  for (int g = 0; g < 3; ++g) {
    int row = g * 128 + w8 * 16 + l16;
    #pragma unroll
    for (int kc = 0; kc < 4; ++kc)
      bq[g][kc] = ldfrag(whh + (size_t)row * H + kc * 32 + quad * 8);
  }
  const float* bhh = ra.bhh[u];
  const float* pre = ra.pre[u];
  float* outf = ra.outf[u];
  unsigned short* outhi = ra.outhi[u];
  unsigned short* outlo = ra.outlo[u];
  unsigned short* agghi = ra.agghi[u];
  unsigned short* agglo = ra.agglo[u];
  int colOff = ra.colOff[u], dir = ra.dir[u];
  int b = ((quad & 1) << 1) | (quad >> 1);
  int d = w8 * 16 + l16;
  float bh_r = bhh[d], bh_z = bhh[d + 128], bh_n = bhh[d + 256];
  float hf = 0.f;
  float ob[8];
  unsigned short obh[8], obl[8];
  int t0 = dir ? (T - 1) : 0;
  const float* pq = pre + (size_t)(b * T + t0) * H3 + d;
  float n_pr = pq[0], n_pz = pq[128], n_pn = pq[256];
  long pst = dir ? -(long)H3 : (long)H3;
  __syncthreads();
  for (int sb = 0; sb < T; sb += 8) {
    #pragma unroll
    for (int ss = 0; ss < 8; ++ss) {
      float pr = n_pr, pz = n_pz, pn = n_pn;
      pq += pst;
      n_pr = pq[0]; n_pz = pq[128]; n_pn = pq[256];
      const unsigned short* hcur = hs[ss & 1];
      unsigned short* hnxt = hs[(ss & 1) ^ 1];
      s16x8 ah[4];
      #pragma unroll
      for (int kc = 0; kc < 4; ++kc)
        ah[kc] = ldfrag(hcur + l16 * 136 + kc * 32 + quad * 8);
      f32x4 accA[3], accB[3];
      #pragma unroll
      for (int g = 0; g < 3; ++g) {
        accA[g] = f32x4{0.f, 0.f, 0.f, 0.f};
        accB[g] = f32x4{0.f, 0.f, 0.f, 0.f};
      }
      #pragma unroll
      for (int g = 0; g < 3; ++g) accA[g] = mfma16(ah[0], bq[g][0], accA[g]);
      #pragma unroll
      for (int g = 0; g < 3; ++g) accB[g] = mfma16(ah[2], bq[g][2], accB[g]);
      #pragma unroll
      for (int g = 0; g < 3; ++g) accA[g] = mfma16(ah[1], bq[g][1], accA[g]);
      #pragma unroll
      for (int g = 0; g < 3; ++g) accB[g] = mfma16(ah[3], bq[g][3], accB[g]);
      float ghv[3];
      #pragma unroll
      for (int g = 0; g < 3; ++g) {
        float x0 = (accA[g][0] + accB[g][0]) + (accA[g][1] + accB[g][1]);
        float x1 = (accA[g][2] + accB[g][2]) + (accA[g][3] + accB[g][3]);
        float y1 = __shfl_xor(x1, 32);      // quad2<-quad0, quad3<-quad1
        ghv[g] = (quad >= 2) ? y1 : x0;
      }
      float rg = sigm(pr + ghv[0] + bh_r);
      float zg = sigm(pz + ghv[1] + bh_z);
      float ng = tanh_f(pn + rg * (ghv[2] + bh_n));
      hf = (1.f - zg) * ng + zg * hf;
      unsigned short hi = f2b(hf);
      unsigned short lo = f2b(hf - b2f(hi));
      hnxt[(2 * b) * 136 + d] = hi;
      hnxt[(2 * b + 1) * 136 + d] = lo;
      ob[ss] = hf; obh[ss] = hi; obl[ss] = lo;
      BAR_LGKM();                           // cross-wave h exchange
    }
    #pragma unroll
    for (int qq = 0; qq < 8; ++qq) {
      int sq = sb + qq;
      int tq = dir ? (T - 1 - sq) : sq;
      size_t o = (size_t)(b * T + tq) * H2 + colOff + d;
      outf[o] = ob[qq]; outhi[o] = obh[qq]; outlo[o] = obl[qq];
      if (agghi) {
        size_t a = (size_t)(b * T + tq) * H12 + colOff + d;
        agghi[a] = obh[qq]; agglo[a] = obl[qq];
      }
    }
  }
}

// ---------------- scores MFMA path v5 (kc-outer, transient fragments) ---------
// grid (1024, 4): y = type*2 + khb. Block stages W⊙h for one i (64 k-rows) into
// 32KB LDS; wave w covers j-tiles w*4..w*4+3. kc-outer loop: per d-chunk, 4
// transient afr ds_reads + 4 transient bf global loads -> 16 MFMAs into
// acc[4][4] (only long-lived state). Everything read once per block.

struct ScMMArgs {
  const unsigned short* Xhi[2];
  const float* Rf; const float* Wt[2]; const float* vt[2];
  float* So[2]; float* So2[2];
};

__global__ __launch_bounds__(256, 2) void k_scmm(ScMMArgs a) {
  __shared__ __align__(16) unsigned short w_lds[64 * 256];   // 32KB swizzled bf16
  int which = blockIdx.y;
  int bi = blockIdx.x, b = bi >> 8;
  int tid = threadIdx.x;
  int type = which >> 1, khb = which & 1;
  const unsigned short* Xhi = a.Xhi[type];
  const float* W = a.Wt[type] + (size_t)khb * 64 * 256;
  const float* v = a.vt[type] + khb * 64;
  float* Sout = khb ? a.So2[type] : a.So[type];
  int lane = tid & 63, w = tid >> 6, quad = lane >> 4, l16 = lane & 15;
  int d4 = tid & 63, rhi = tid >> 6;
  float4 h4 = ((const float4*)(a.Rf + (size_t)bi * 256))[d4];
  #pragma unroll
  for (int it = 0; it < 16; ++it) {
    int kl = it * 4 + rhi;                            // local row 0..63
    float4 w4 = ((const float4*)(W + (size_t)kl * 256))[d4];
    unsigned lo32 = cvt_pk_bf16(w4.x * h4.x, w4.y * h4.y);
    unsigned hi32 = cvt_pk_bf16(w4.z * h4.z, w4.w * h4.w);
    unsigned long long pk = (unsigned long long)lo32 | ((unsigned long long)hi32 << 32);
    int gphys = ((d4 >> 1) + kl) & 31;
    *(unsigned long long*)(w_lds + (size_t)kl * 256 + gphys * 8 + (d4 & 1) * 4) = pk;
  }
  BAR_LGKM();
  // kc-outer: acc[jj][c] accumulates over 8 d-chunks; fragments transient.
  f32x4 acc[4][4];
  #pragma unroll
  for (int jj = 0; jj < 4; ++jj)
    #pragma unroll
    for (int c = 0; c < 4; ++c) acc[jj][c] = f32x4{0.f, 0.f, 0.f, 0.f};
  const unsigned short* Xp0 =
      Xhi + (size_t)(b * 256 + w * 4 * 16 + l16) * 256 + quad * 8;
  #pragma unroll 2
  for (int kc = 0; kc < 8; ++kc) {
    s16x8 af[4];
    #pragma unroll
    for (int c = 0; c < 4; ++c) {
      int krow = c * 16 + l16;
      int gp = (kc * 4 + quad + krow) & 31;
      af[c] = ldfrag(w_lds + (size_t)krow * 256 + gp * 8);
    }
    s16x8 bf[4];
    #pragma unroll
    for (int jj = 0; jj < 4; ++jj)
      bf[jj] = ldfrag(Xp0 + (size_t)jj * 16 * 256 + kc * 32);
    #pragma unroll
    for (int jj = 0; jj < 4; ++jj)
      #pragma unroll
      for (int c = 0; c < 4; ++c)
        acc[jj][c] = mfma16(af[c], bf[jj], acc[jj][c]);
  }
  float vv[4][4];
  #pragma unroll
  for (int c = 0; c < 4; ++c)
    #pragma unroll
    for (int r = 0; r < 4; ++r) vv[c][r] = v[c * 16 + quad * 4 + r];
  #pragma unroll
  for (int jj = 0; jj < 4; ++jj) {
    float s = 0.f;
    #pragma unroll
    for (int c = 0; c < 4; ++c)
      #pragma unroll
      for (int r = 0; r < 4; ++r) s += tanh_f(acc[jj][c][r]) * vv[c][r];
    s += __shfl_xor(s, 16);
    s += __shfl_xor(s, 32);
    int jt = w * 4 + jj;
    if (lane < 16) Sout[(size_t)bi * 256 + jt * 16 + l16] = s;
  }
}

// ---------------- scores cmb path (separate dispatch, grid 128) ---------------

struct ScCmbArgs {
  const float *Hc, *Rc, *Hm, *Rm, *HB, *hrf, *vcf, *vmf; float* S;
};

__global__ __launch_bounds__(256, 2) void k_sccmb(ScCmbArgs a) {
  int bi = blockIdx.x;
  int tid = threadIdx.x;
  __shared__ float rc_l[8 * 128];
  __shared__ float rm_l[8 * 128];
  __shared__ float hr_l[8 * 256];
  __shared__ float vc_l[128], vm_l[128];
  int b = bi >> 5, i0 = (bi & 31) << 3;       // 8 i-rows: gi0..gi0+7
  int gi0 = b * 256 + i0;
  {
    const float4* rc4 = (const float4*)(a.Rc + (size_t)gi0 * 128);
    const float4* rm4 = (const float4*)(a.Rm + (size_t)gi0 * 128);
    ((float4*)rc_l)[tid] = rc4[tid];
    ((float4*)rm_l)[tid] = rm4[tid];
    const float4* hr4 = (const float4*)(a.hrf + (size_t)gi0 * 256);
    ((float4*)hr_l)[tid] = hr4[tid];
    ((float4*)hr_l)[256 + tid] = hr4[256 + tid];
    if (tid < 128) { vc_l[tid] = a.vcf[tid]; vm_l[tid] = a.vmf[tid]; }
  }
  __syncthreads();
  int j = tid;
  size_t cb = (size_t)(b * 256 + j);
  float scq[8], smq[8], sbq[8];
  #pragma unroll
  for (int q = 0; q < 8; ++q) { scq[q] = 0.f; smq[q] = 0.f; sbq[q] = 0.f; }
  for (int k = 0; k < 128; ++k) {
    float hc = a.Hc[(size_t)k * M + cb];      // transposed: lane-consecutive
    float hm = a.Hm[(size_t)k * M + cb];
    float vck = vc_l[k], vmk = vm_l[k];
    #pragma unroll
    for (int q = 0; q < 8; ++q) {
      scq[q] += vck * tanh_f(hc + rc_l[q * 128 + k]);
      smq[q] += vmk * tanh_f(hm - rm_l[q * 128 + k]);
    }
  }
  for (int k = 0; k < 256; ++k) {
    float hb = a.HB[(size_t)k * M + cb];      // transposed
    #pragma unroll
    for (int q = 0; q < 8; ++q) sbq[q] += hb * hr_l[q * 256 + k];
  }
  #pragma unroll
  for (int q = 0; q < 8; ++q) {
    size_t o = (size_t)(gi0 + q) * 256 + j;
    a.S[(size_t)STY * 1 + o] = scq[q];
    a.S[(size_t)STY * 3 + o] = sbq[q];
    a.S[(size_t)STY * 4 + o] = smq[q];
  }
}

// ---------------- wsum with inline softmax (adds kh-half partials) ------------

__global__ __launch_bounds__(256) void k_wsum(const float* __restrict__ S,
    const float* __restrict__ S2,
    const float* __restrict__ hl_f, const float* __restrict__ hr_f,
    unsigned short* __restrict__ ahi, unsigned short* __restrict__ alo) {
  int it = blockIdx.x, type = blockIdx.y, b = blockIdx.z;
  __shared__ float p_l[8][256];
  __shared__ float red[4];
  int tid = threadIdx.x;
  for (int ii = 0; ii < 8; ++ii) {
    size_t idx = ((size_t)(b * 256 + it * 8 + ii)) * 256 + tid;
    float x = S[(size_t)type * STY + idx];
    if (type == 0) x += S2[idx];                        // pts partial (kh1)
    else if (type == 2) x += S2[(size_t)STY + idx];     // ptd partial (kh1)
    float m = x;
    for (int dl = 32; dl; dl >>= 1) m = fmaxf(m, __shfl_xor(m, dl));
    if ((tid & 63) == 0) red[tid >> 6] = m;
    __syncthreads();
    m = fmaxf(fmaxf(red[0], red[1]), fmaxf(red[2], red[3]));
    __syncthreads();
    float e = __expf(x - m);
    float sum = e;
    for (int dl = 32; dl; dl >>= 1) sum += __shfl_xor(sum, dl);
    if ((tid & 63) == 0) red[tid >> 6] = sum;
    __syncthreads();
    sum = red[0] + red[1] + red[2] + red[3];
    p_l[ii][tid] = e * rcp_f(sum);
    __syncthreads();
  }
  const float* src = (type == 0 ? hr_f : hl_f) + (size_t)b * 256 * 256;
  float acc[8] = {0.f, 0.f, 0.f, 0.f, 0.f, 0.f, 0.f, 0.f};
  for (int j = 0; j < 256; ++j) {
    float hv = src[(size_t)j * 256 + tid];
    #pragma unroll
    for (int ii = 0; ii < 8; ++ii) acc[ii] += p_l[ii][j] * hv;
  }
  int off = 256 * (1 + type);      // agg: [hr | pts | ptc | ptd | ptb | ptm]
  #pragma unroll
  for (int ii = 0; ii < 8; ++ii) {
    float vv = acc[ii];
    unsigned short hi = f2b(vv);
    size_t o = (size_t)(b * 256 + it * 8 + ii) * H12 + off + tid;
    ahi[o] = hi;
    alo[o] = f2b(vv - b2f(hi));
  }
}

// ---------------- fused tail ----------------

__global__ __launch_bounds__(256) void k_tail(const float* __restrict__ Hp,
    const float* __restrict__ hl_f, const float* __restrict__ vpf,
    const float* __restrict__ Wc2f, const float* __restrict__ Arc,
    const float* __restrict__ ar_f, const float* __restrict__ vcf,
    const float* __restrict__ Wpredf, float* __restrict__ out) {
  int b = blockIdx.x, tid = threadIdx.x;
  __shared__ float vl[128], wl[256], rvec[256], rlcl[128], red[4];
  if (tid < 128) vl[tid] = vpf[tid];
  __syncthreads();
  const float* hp = Hp + (size_t)(b * 256 + tid) * 128;
  float s = 0.f;
  for (int k = 0; k < 128; ++k) s += vl[k] * tanh_f(hp[k]);
  float m = s;
  for (int dl = 32; dl; dl >>= 1) m = fmaxf(m, __shfl_xor(m, dl));
  if ((tid & 63) == 0) red[tid >> 6] = m;
  __syncthreads();
  m = fmaxf(fmaxf(red[0], red[1]), fmaxf(red[2], red[3]));
  __syncthreads();
  float e = __expf(s - m);
  float sum = e;
  for (int dl = 32; dl; dl >>= 1) sum += __shfl_xor(sum, dl);
  if ((tid & 63) == 0) red[tid >> 6] = sum;
  __syncthreads();
  sum = red[0] + red[1] + red[2] + red[3];
  wl[tid] = e * rcp_f(sum);
  __syncthreads();
  float acc = 0.f;
  for (int t = 0; t < 256; ++t) acc += wl[t] * hl_f[(size_t)(b * 256 + t) * 256 + tid];
  rvec[tid] = acc;
  __syncthreads();
  if (tid < 128) {
    float a2 = 0.f;
    const float* wr = Wc2f + (size_t)tid * 256;
    for (int dk = 0; dk < 256; ++dk) a2 += rvec[dk] * wr[dk];
    rlcl[tid] = a2;
    vl[tid] = vcf[tid];
  }
  __syncthreads();
  const float* ap = Arc + (size_t)(b * 256 + tid) * 128;
  float s2 = 0.f;
  for (int k = 0; k < 128; ++k) s2 += vl[k] * (ap[k] + rlcl[k]);
  m = s2;
  for (int dl = 32; dl; dl >>= 1) m = fmaxf(m, __shfl_xor(m, dl));
  if ((tid & 63) == 0) red[tid >> 6] = m;
  __syncthreads();
  m = fmaxf(fmaxf(red[0], red[1]), fmaxf(red[2], red[3]));
  __syncthreads();
  float e2 = __expf(s2 - m);
  float sum2 = e2;
  for (int dl = 32; dl; dl >>= 1) sum2 += __shfl_xor(sum2, dl);
  if ((tid & 63) == 0) red[tid >> 6] = sum2;
  __syncthreads();
  sum2 = red[0] + red[1] + red[2] + red[3];
  wl[tid] = e2 * rcp_f(sum2);
  __syncthreads();
  float acc2 = 0.f;
  for (int t = 0; t < 256; ++t) acc2 += wl[t] * ar_f[(size_t)(b * 256 + t) * 256 + tid];
  rvec[tid] = acc2;
  __syncthreads();
  if (tid < 2) {
    float o = 0.f;
    const float* wp = Wpredf + (size_t)tid * 256;
    for (int dk = 0; dk < 256; ++dk) o += rvec[dk] * wp[dk];
    out[b * 2 + tid] = sigm(o);
  }
}

// ---------------- host ----------------

extern "C" void kernel_launch(void* const* d_in, const int* in_sizes, int n_in,
                              void* d_out, int out_size, void* d_ws, size_t ws_size,
                              hipStream_t stream) {
  (void)in_sizes; (void)n_in; (void)out_size; (void)ws_size;
  const int* inputs = (const int*)d_in[0];
  const float* embed = (const float*)d_in[1];
  const float* lWih = (const float*)d_in[2];
  const float* lWhh = (const float*)d_in[3];
  const float* lbih = (const float*)d_in[4];
  const float* lbhh = (const float*)d_in[5];
  const float* rWih = (const float*)d_in[6];
  const float* rWhh = (const float*)d_in[7];
  const float* rbih = (const float*)d_in[8];
  const float* rbhh = (const float*)d_in[9];
  const float* aWih = (const float*)d_in[10];
  const float* aWhh = (const float*)d_in[11];
  const float* abih = (const float*)d_in[12];
  const float* abhh = (const float*)d_in[13];
  const float* Wc1 = (const float*)d_in[14];
  const float* Wc2 = (const float*)d_in[15];
  const float* vc  = (const float*)d_in[16];
  const float* Wb  = (const float*)d_in[17];
  const float* Wd  = (const float*)d_in[18];
  const float* vd  = (const float*)d_in[19];
  const float* Wm  = (const float*)d_in[20];
  const float* vmv = (const float*)d_in[21];
  const float* Wsw = (const float*)d_in[22];
  const float* vsv = (const float*)d_in[23];
  const float* Wp  = (const float*)d_in[24];
  const float* vp  = (const float*)d_in[25];
  const float* Wpred = (const float*)d_in[26];

  char* ws = (char*)d_ws;
  size_t off = 0;
  auto alloc = [&](size_t bytes) -> void* {
    void* p = ws + off;
    off += (bytes + 255) & ~(size_t)255;
    return p;
  };
  unsigned short* xhi = (unsigned short*)alloc((size_t)M * EP * 2);
  unsigned short* xlo = (unsigned short*)alloc((size_t)M * EP * 2);
  unsigned short* wpad = (unsigned short*)alloc((size_t)4 * H3 * EP * 2);
  unsigned short* Whh_b = (unsigned short*)alloc((size_t)6 * H3 * H * 2);
  unsigned short* aWih_b = (unsigned short*)alloc((size_t)2 * H3 * H12 * 2);
  unsigned short* Wc1_b = (unsigned short*)alloc((size_t)H * H2 * 2);
  unsigned short* Wc2_b = (unsigned short*)alloc((size_t)H * H2 * 2);
  unsigned short* Wm_b  = (unsigned short*)alloc((size_t)H * H2 * 2);
  unsigned short* Wp_b  = (unsigned short*)alloc((size_t)H * H2 * 2);
  unsigned short* Wb_b  = (unsigned short*)alloc((size_t)H2 * H2 * 2);
  char* region1 = (char*)alloc((size_t)4 * M * H3 * 4);
  float* pre_lr = (float*)region1;
  float* S      = (float*)region1;
  float* pre_a  = (float*)region1;
  float* S2 = (float*)alloc((size_t)2 * STY * 4);   // kh1 partials: [pts | ptd]
  float* hl_f = (float*)alloc((size_t)M * H2 * 4);
  float* hr_f = (float*)alloc((size_t)M * H2 * 4);
  unsigned short* hl_hi = (unsigned short*)alloc((size_t)M * H2 * 2);
  unsigned short* hl_lo = (unsigned short*)alloc((size_t)M * H2 * 2);
  unsigned short* hr_hi = (unsigned short*)alloc((size_t)M * H2 * 2);
  unsigned short* hr_lo = (unsigned short*)alloc((size_t)M * H2 * 2);
  float* Hc = (float*)alloc((size_t)M * H * 4);     // transposed [H][M]
  float* Rc = (float*)alloc((size_t)M * H * 4);
  float* Hm = (float*)alloc((size_t)M * H * 4);     // transposed [H][M]
  float* Rm = (float*)alloc((size_t)M * H * 4);
  float* Hp = (float*)alloc((size_t)M * H * 4);
  float* HB = (float*)alloc((size_t)M * H2 * 4);    // transposed [H2][M]
  unsigned short* agg_hi = (unsigned short*)alloc((size_t)M * H12 * 2);
  unsigned short* agg_lo = (unsigned short*)alloc((size_t)M * H12 * 2);
  float* ar_f = (float*)alloc((size_t)M * H2 * 4);
  unsigned short* ar_hi = (unsigned short*)alloc((size_t)M * H2 * 2);
  unsigned short* ar_lo = (unsigned short*)alloc((size_t)M * H2 * 2);
  float* Arc = (float*)alloc((size_t)M * H * 4);

  // 1. staging
  StageArgs sa{};
  sa.cs[0] = lWhh;  sa.cd[0] = Whh_b;                 sa.cn[0] = 2 * H3 * H;
  sa.cs[1] = rWhh;  sa.cd[1] = Whh_b + 2 * H3 * H;    sa.cn[1] = 2 * H3 * H;
  sa.cs[2] = aWhh;  sa.cd[2] = Whh_b + 4 * H3 * H;    sa.cn[2] = 2 * H3 * H;
  sa.cs[3] = aWih;  sa.cd[3] = aWih_b;                sa.cn[3] = 2 * H3 * H12;
  sa.cs[4] = Wc1;   sa.cd[4] = Wc1_b;                 sa.cn[4] = H * H2;
  sa.cs[5] = Wc2;   sa.cd[5] = Wc2_b;                 sa.cn[5] = H * H2;
  sa.cs[6] = Wm;    sa.cd[6] = Wm_b;                  sa.cn[6] = H * H2;
  sa.cs[7] = Wp;    sa.cd[7] = Wp_b;                  sa.cn[7] = H * H2;
  sa.cs[8] = Wb;    sa.cd[8] = Wb_b;                  sa.cn[8] = H2 * H2;
  sa.idx = inputs; sa.emb = embed; sa.xhi = xhi; sa.xlo = xlo;
  sa.lW = lWih; sa.rW = rWih; sa.wpad = wpad;
  k_stage<<<dim3((2 * H3 * H12 + 255) / 256, 11), dim3(256), 0, stream>>>(sa);

  // 2. input projections for l/r GRUs
  GemmBatch ga{};
  const float* biases[4] = { lbih, lbih + H3, rbih, rbih + H3 };
  for (int u = 0; u < 4; ++u)
    ga.d[u] = GemmDesc{ xhi, xlo, wpad + (size_t)u * H3 * EP, biases[u],
                        pre_lr + (size_t)u * M * H3, H3, EP, 0 };
  k_gemm<<<dim3(16, 6, 4), dim3(256), 0, stream>>>(ga);

  // 3. l/r recurrences (writes fp32 + hi/lo + agg hr-copy); 1 unit per block
  RecArgs r1{};
  r1.whh[0] = Whh_b;               r1.whh[1] = Whh_b + H3 * H;
  r1.whh[2] = Whh_b + 2 * H3 * H;  r1.whh[3] = Whh_b + 3 * H3 * H;
  for (int u = 0; u < 4; ++u) r1.pre[u] = pre_lr + (size_t)u * M * H3;
  r1.outf[0] = r1.outf[1] = hl_f; r1.outf[2] = r1.outf[3] = hr_f;
  r1.outhi[0] = r1.outhi[1] = hl_hi; r1.outhi[2] = r1.outhi[3] = hr_hi;
  r1.outlo[0] = r1.outlo[1] = hl_lo; r1.outlo[2] = r1.outlo[3] = hr_lo;
  r1.agghi[0] = r1.agghi[1] = nullptr; r1.agghi[2] = r1.agghi[3] = agg_hi;
  r1.agglo[0] = r1.agglo[1] = nullptr; r1.agglo[2] = r1.agglo[3] = agg_lo;
  r1.bhh[0] = lbhh; r1.bhh[1] = lbhh + H3; r1.bhh[2] = rbhh; r1.bhh[3] = rbhh + H3;
  r1.colOff[0] = 0; r1.colOff[1] = H; r1.colOff[2] = 0; r1.colOff[3] = H;
  r1.dir[0] = 0; r1.dir[1] = 1; r1.dir[2] = 0; r1.dir[3] = 1;
  k_gru<<<dim3(4), dim3(512), 0, stream>>>(r1);

  // 4. projection GEMMs (Hc/Hm/HB transposed for the j-streamed cmb path)
  GemmBatch gbB{};
  gbB.d[0] = GemmDesc{ hl_hi, hl_lo, Wc1_b, nullptr, Hc, H, H2, 1 };
  gbB.d[1] = GemmDesc{ hr_hi, hr_lo, Wc2_b, nullptr, Rc, H, H2, 0 };
  gbB.d[2] = GemmDesc{ hl_hi, hl_lo, Wm_b, nullptr, Hm, H, H2, 1 };
  gbB.d[3] = GemmDesc{ hr_hi, hr_lo, Wm_b, nullptr, Rm, H, H2, 0 };
  gbB.d[4] = GemmDesc{ hl_hi, hl_lo, Wb_b, nullptr, HB, H2, H2, 1 };
  gbB.d[5] = GemmDesc{ hl_hi, hl_lo, Wp_b, nullptr, Hp, H, H2, 0 };
  k_gemm<<<dim3(16, 4, 6), dim3(256), 0, stream>>>(gbB);

  // 5a. MFMA scores (pts/ptd halves)
  ScMMArgs sm{};
  sm.Xhi[0] = hl_hi; sm.Wt[0] = Wd;  sm.vt[0] = vd;  sm.So[0] = S + (size_t)2 * STY;
  sm.Xhi[1] = hr_hi; sm.Wt[1] = Wsw; sm.vt[1] = vsv; sm.So[1] = S + (size_t)0 * STY;
  sm.So2[0] = S2 + (size_t)STY;   // ptd kh1 partial
  sm.So2[1] = S2;                 // pts kh1 partial
  sm.Rf = hr_f;
  k_scmm<<<dim3(M, 4), dim3(256), 0, stream>>>(sm);

  // 5b. combined ptc/ptb/ptm scores
  ScCmbArgs scb{};
  scb.Hc = Hc; scb.Rc = Rc; scb.Hm = Hm; scb.Rm = Rm; scb.HB = HB;
  scb.hrf = hr_f; scb.vcf = vc; scb.vmf = vmv; scb.S = S;
  k_sccmb<<<dim3(128), dim3(256), 0, stream>>>(scb);

  // 6. softmax + weighted sums into agg
  k_wsum<<<dim3(32, 5, 4), dim3(256), 0, stream>>>(S, S2, hl_f, hr_f, agg_hi, agg_lo);

  // 7. agg GRU input projection
  GemmBatch gc{};
  gc.d[0] = GemmDesc{ agg_hi, agg_lo, aWih_b, abih, pre_a, H3, H12, 0 };
  gc.d[1] = GemmDesc{ agg_hi, agg_lo, aWih_b + (size_t)H3 * H12, abih + H3,
                      pre_a + (size_t)M * H3, H3, H12, 0 };
  k_gemm<<<dim3(16, 6, 2), dim3(256), 0, stream>>>(gc);

  // 8. agg recurrence (writes ar fp32 + hi/lo); 1 unit per block
  RecArgs r2{};
  r2.whh[0] = Whh_b + 4 * H3 * H; r2.whh[1] = Whh_b + 5 * H3 * H;
  r2.whh[2] = r2.whh[3] = Whh_b + 4 * H3 * H;
  r2.pre[0] = pre_a; r2.pre[1] = pre_a + (size_t)M * H3;
  r2.pre[2] = r2.pre[3] = pre_a;
  r2.outf[0] = r2.outf[1] = r2.outf[2] = r2.outf[3] = ar_f;
  r2.outhi[0] = r2.outhi[1] = r2.outhi[2] = r2.outhi[3] = ar_hi;
  r2.outlo[0] = r2.outlo[1] = r2.outlo[2] = r2.outlo[3] = ar_lo;
  for (int u = 0; u < 4; ++u) { r2.agghi[u] = nullptr; r2.agglo[u] = nullptr; }
  r2.bhh[0] = abhh; r2.bhh[1] = abhh + H3; r2.bhh[2] = r2.bhh[3] = abhh;
  r2.colOff[0] = 0; r2.colOff[1] = H; r2.colOff[2] = r2.colOff[3] = 0;
  r2.dir[0] = 0; r2.dir[1] = 1; r2.dir[2] = r2.dir[3] = 0;
  k_gru<<<dim3(2), dim3(512), 0, stream>>>(r2);

  // 9. Arc GEMM
  GemmBatch gd{};
  gd.d[0] = GemmDesc{ ar_hi, ar_lo, Wc1_b, nullptr, Arc, H, H2, 0 };
  k_gemm<<<dim3(16, 2, 1), dim3(256), 0, stream>>>(gd);

  // 10. fused tail
  k_tail<<<dim3(4), dim3(256), 0, stream>>>(Hp, hl_f, vp, Wc2, Arc, ar_f, vc, Wpred,
                                            (float*)d_out);
}

// Round 8
// 719.988 us; speedup vs baseline: 1.0394x; 1.0394x over previous
//
#include <hip/hip_runtime.h>

// MANNet forward, MI355X gfx950. Inputs fp32 (+int32 ids), output fp32.
// R17: k_gru v6 — critical-path surgery. 1380 cy/step was exposed latency:
// (1) __shfl_xor(,32) x3 = LDS-routed ds_permute on the h-chain -> replaced by
//     v_permlane32_swap_b32 (1 VALU op; r[0] = {vdst.lo32, vsrc.lo32} is exactly
//     the quad<2?x0:x1-from-low-half select).
// (2) MFMAs reordered gate-major (R, Z, then N) with combines interleaved so
//     rg/zg's exp+rcp chains run on the VALU pipe WHILE later-gate MFMAs execute.
// (3) per-step streamed output stores (no 8-step flush bubble) + depth-2 pre
//     prefetch (even/odd register pairs, bh_r/bh_z pre-added at prefetch).

#define DEV static __device__ __forceinline__
#define BAR_LGKM() __asm__ volatile("s_waitcnt lgkmcnt(0)\ns_barrier" ::: "memory")

typedef __attribute__((ext_vector_type(4))) float f32x4;
typedef __attribute__((ext_vector_type(8))) short s16x8;
typedef __attribute__((ext_vector_type(4))) unsigned int u32x4;
typedef __attribute__((ext_vector_type(2))) unsigned int u32x2;

constexpr int T = 256, E = 300, EP = 320, H = 128, H2 = 256, H3 = 384, H12 = 1536;
constexpr int M = 1024;            // B*T
constexpr int STY = 262144;        // 4*T*T elements per score type

DEV float b2f(unsigned short h) { return __uint_as_float(((unsigned)h) << 16); }
DEV unsigned short f2b(float f) {
  unsigned u = __float_as_uint(f);
  u += 0x7fff + ((u >> 16) & 1);            // RNE
  return (unsigned short)(u >> 16);
}
DEV unsigned cvt_pk_bf16(float lo, float hi) {   // dst = {bf16(lo), bf16(hi)} RNE
  unsigned r;
  __asm__("v_cvt_pk_bf16_f32 %0, %1, %2" : "=v"(r) : "v"(lo), "v"(hi));
  return r;
}
DEV float rcp_f(float x) {                       // v_rcp_f32: 1 ulp, 1 trans op
  float r;
  __asm__("v_rcp_f32 %0, %1" : "=v"(r) : "v"(x));
  return r;
}
DEV float sigm(float x) { return rcp_f(1.f + __expf(-x)); }
DEV float tanh_f(float x) {
  float e = __expf(2.f * x);
  return __builtin_fmaf(-2.f, rcp_f(e + 1.f), 1.f);
}
// lanes 0-31 <- x0, lanes 32-63 <- x1's lanes 0-31 (one v_permlane32_swap_b32)
DEV float plsel(float x0, float x1) {
  u32x2 r = __builtin_amdgcn_permlane32_swap(
      __float_as_uint(x0), __float_as_uint(x1), false, false);
  return __uint_as_float(r[0]);
}

DEV s16x8 ldfrag(const unsigned short* p) {
  u32x4 v = *(const u32x4*)p;
  return __builtin_bit_cast(s16x8, v);
}
DEV f32x4 mfma16(s16x8 a, s16x8 b, f32x4 c) {
  return __builtin_amdgcn_mfma_f32_16x16x32_bf16(a, b, c, 0, 0, 0);
}

// ---------------- fused staging: 9x cvt + embed + padw ----------------

struct StageArgs {
  const float* cs[9]; unsigned short* cd[9]; int cn[9];
  const int* idx; const float* emb; unsigned short* xhi; unsigned short* xlo;
  const float* lW; const float* rW; unsigned short* wpad;
};

__global__ void k_stage(StageArgs sa) {
  int seg = blockIdx.y;
  int i = blockIdx.x * 256 + threadIdx.x;
  if (seg < 9) {
    if (i < sa.cn[seg]) sa.cd[seg][i] = f2b(sa.cs[seg][i]);
    return;
  }
  if (seg == 9) {
    if (i >= M * EP) return;
    int m = i / EP, e = i - m * EP;
    int r = sa.idx[m];
    float v = (e < E) ? sa.emb[(size_t)r * E + e] : 0.f;
    unsigned short hi = f2b(v);
    sa.xhi[i] = hi;
    sa.xlo[i] = f2b(v - b2f(hi));
    return;
  }
  if (i >= 4 * H3 * EP) return;
  int e = i % EP, n = (i / EP) % H3, uu = i / (EP * H3);
  const float* src = (uu < 2 ? sa.lW : sa.rW) + (size_t)((uu & 1) * H3 + n) * E;
  sa.wpad[i] = (e < E) ? f2b(src[e]) : (unsigned short)0;
}

// ---------------- generic GEMM: C = (Ahi+Alo) @ W^T (+bias), fp32 out ----------
// tr=1: write transposed C_t[n*M + m] (for j-streamed consumers).

struct GemmDesc {
  const unsigned short* Ahi; const unsigned short* Alo; const unsigned short* W;
  const float* bias; float* Cf; int N; int K; int tr;
};
struct GemmBatch { GemmDesc d[8]; };

__global__ __launch_bounds__(256) void k_gemm(GemmBatch gb) {
  GemmDesc g = gb.d[blockIdx.z];
  int nb = blockIdx.y * 64;
  if (nb >= g.N) return;
  int mb = blockIdx.x * 64;
  int lane = threadIdx.x & 63, w = threadIdx.x >> 6, quad = lane >> 4, l16 = lane & 15;
  int K = g.K;
  const unsigned short* Ahp = g.Ahi + (size_t)(mb + w * 16 + l16) * K + quad * 8;
  const unsigned short* Alp = g.Alo + (size_t)(mb + w * 16 + l16) * K + quad * 8;
  const unsigned short* Wp = g.W + (size_t)(nb + l16) * K + quad * 8;
  f32x4 acc[4];
  #pragma unroll
  for (int nt = 0; nt < 4; ++nt) acc[nt] = f32x4{0.f, 0.f, 0.f, 0.f};
  for (int k = 0; k < K; k += 32) {
    s16x8 ah = ldfrag(Ahp + k);
    s16x8 al = ldfrag(Alp + k);
    #pragma unroll
    for (int nt = 0; nt < 4; ++nt) {
      s16x8 b = ldfrag(Wp + (size_t)nt * 16 * K + k);
      acc[nt] = mfma16(ah, b, acc[nt]);
      acc[nt] = mfma16(al, b, acc[nt]);
    }
  }
  int mr0 = mb + w * 16 + quad * 4;
  #pragma unroll
  for (int nt = 0; nt < 4; ++nt) {
    int col = nb + nt * 16 + l16;
    float bv = g.bias ? g.bias[col] : 0.f;
    #pragma unroll
    for (int r = 0; r < 4; ++r) {
      if (g.tr)
        g.Cf[(size_t)col * M + (mr0 + r)] = acc[nt][r] + bv;
      else
        g.Cf[(size_t)(mr0 + r) * g.N + col] = acc[nt][r] + bv;
    }
  }
}

// ---------------- GRU recurrence v6 ----------------

struct RecArgs {
  const unsigned short* whh[4];
  const float* pre[4];
  float* outf[4];
  unsigned short* outhi[4];
  unsigned short* outlo[4];
  unsigned short* agghi[4];      // null -> no agg copy
  unsigned short* agglo[4];
  const float* bhh[4];
  int colOff[4];
  int dir[4];
};

// One recurrence step. pr_/pz_/pn_ are this step's pre-activations (bh_r/bh_z
// pre-added); they are refreshed from pq_ (advanced 2 steps) for step s+2.
#define GRU_STEP(pr_, pz_, pn_, pq_, hcur_, hnxt_, s_)                         \
  {                                                                            \
    float pr = pr_, pz = pz_, pn = pn_;                                        \
    pq_ += pst2;                                                               \
    pr_ = pq_[0] + bh_r; pz_ = pq_[128] + bh_z; pn_ = pq_[256];                \
    const unsigned short* hb_ = hcur_ + l16 * 136 + quad * 8;                  \
    s16x8 ah0 = ldfrag(hb_);                                                   \
    s16x8 ah1 = ldfrag(hb_ + 32);                                              \
    s16x8 ah2 = ldfrag(hb_ + 64);                                              \
    s16x8 ah3 = ldfrag(hb_ + 96);                                              \
    f32x4 z4 = f32x4{0.f, 0.f, 0.f, 0.f};                                      \
    f32x4 aR0 = mfma16(ah0, bq[0][0], z4);                                     \
    f32x4 aR1 = mfma16(ah2, bq[0][2], z4);                                     \
    aR0 = mfma16(ah1, bq[0][1], aR0);                                          \
    aR1 = mfma16(ah3, bq[0][3], aR1);                                          \
    f32x4 aZ0 = mfma16(ah0, bq[1][0], z4);                                     \
    f32x4 aZ1 = mfma16(ah2, bq[1][2], z4);                                     \
    aZ0 = mfma16(ah1, bq[1][1], aZ0);                                          \
    aZ1 = mfma16(ah3, bq[1][3], aZ1);                                          \
    float r0 = (aR0[0] + aR1[0]) + (aR0[1] + aR1[1]);                          \
    float r1v = (aR0[2] + aR1[2]) + (aR0[3] + aR1[3]);                         \
    float rg = sigm(pr + plsel(r0, r1v));                                      \
    f32x4 aN0 = mfma16(ah0, bq[2][0], z4);                                     \
    f32x4 aN1 = mfma16(ah2, bq[2][2], z4);                                     \
    aN0 = mfma16(ah1, bq[2][1], aN0);                                          \
    aN1 = mfma16(ah3, bq[2][3], aN1);                                          \
    float z0 = (aZ0[0] + aZ1[0]) + (aZ0[1] + aZ1[1]);                          \
    float z1 = (aZ0[2] + aZ1[2]) + (aZ0[3] + aZ1[3]);                          \
    float zg = sigm(pz + plsel(z0, z1));                                       \
    float n0 = (aN0[0] + aN1[0]) + (aN0[1] + aN1[1]);                          \
    float n1 = (aN0[2] + aN1[2]) + (aN0[3] + aN1[3]);                          \
    float ng = tanh_f(pn + rg * (plsel(n0, n1) + bh_n));                       \
    hf = __builtin_fmaf(zg, hf - ng, ng);                                      \
    unsigned short hi = f2b(hf);                                               \
    unsigned short lo = f2b(hf - b2f(hi));                                     \
    hnxt_[(2 * b) * 136 + d] = hi;                                             \
    hnxt_[(2 * b + 1) * 136 + d] = lo;                                         \
    int tq = dir ? (T - 1 - (s_)) : (s_);                                      \
    size_t o_ = (size_t)(b * T + tq) * H2 + colOff + d;                        \
    outf[o_] = hf; outhi[o_] = hi; outlo[o_] = lo;                             \
    if (agghi) {                                                               \
      size_t a_ = (size_t)(b * T + tq) * H12 + colOff + d;                     \
      agghi[a_] = hi; agglo[a_] = lo;                                          \
    }                                                                          \
    BAR_LGKM();                                                                \
  }

__global__ __launch_bounds__(512) void k_gru(RecArgs ra) {
  int u = blockIdx.x;
  __shared__ __align__(16) unsigned short hs[2][16 * 136];
  int tid = threadIdx.x, lane = tid & 63, w8 = tid >> 6;
  int quad = lane >> 4, l16 = lane & 15;
  for (int i = tid; i < 2 * 16 * 136; i += 512) ((unsigned short*)hs)[i] = 0;
  const unsigned short* whh = ra.whh[u];
  s16x8 bq[3][4];
  #pragma unroll
  for (int g = 0; g < 3; ++g) {
    int row = g * 128 + w8 * 16 + l16;
    #pragma unroll
    for (int kc = 0; kc < 4; ++kc)
      bq[g][kc] = ldfrag(whh + (size_t)row * H + kc * 32 + quad * 8);
  }
  const float* bhh = ra.bhh[u];
  const float* pre = ra.pre[u];
  float* outf = ra.outf[u];
  unsigned short* outhi = ra.outhi[u];
  unsigned short* outlo = ra.outlo[u];
  unsigned short* agghi = ra.agghi[u];
  unsigned short* agglo = ra.agglo[u];
  int colOff = ra.colOff[u], dir = ra.dir[u];
  int b = ((quad & 1) << 1) | (quad >> 1);
  int d = w8 * 16 + l16;
  float bh_r = bhh[d], bh_z = bhh[d + 128], bh_n = bhh[d + 256];
  float hf = 0.f;
  int t0 = dir ? (T - 1) : 0;
  long pst = dir ? -(long)H3 : (long)H3;
  long pst2 = 2 * pst;
  // depth-2 prefetch: even/odd register pairs. Final iterations overrun the
  // unit's pre slab by <=2 rows (3KB) — lands in adjacent ws regions, unused.
  const float* pqE = pre + (size_t)(b * T + t0) * H3 + d;
  const float* pqO = pqE + pst;
  float e_pr = pqE[0] + bh_r, e_pz = pqE[128] + bh_z, e_pn = pqE[256];
  float o_pr = pqO[0] + bh_r, o_pz = pqO[128] + bh_z, o_pn = pqO[256];
  __syncthreads();
  for (int s = 0; s < T; s += 2) {
    GRU_STEP(e_pr, e_pz, e_pn, pqE, hs[0], hs[1], s);
    GRU_STEP(o_pr, o_pz, o_pn, pqO, hs[1], hs[0], s + 1);
  }
}

// ---------------- scores MFMA path v5 (kc-outer, transient fragments) ---------

struct ScMMArgs {
  const unsigned short* Xhi[2];
  const float* Rf; const float* Wt[2]; const float* vt[2];
  float* So[2]; float* So2[2];
};

__global__ __launch_bounds__(256, 2) void k_scmm(ScMMArgs a) {
  __shared__ __align__(16) unsigned short w_lds[64 * 256];   // 32KB swizzled bf16
  int which = blockIdx.y;
  int bi = blockIdx.x, b = bi >> 8;
  int tid = threadIdx.x;
  int type = which >> 1, khb = which & 1;
  const unsigned short* Xhi = a.Xhi[type];
  const float* W = a.Wt[type] + (size_t)khb * 64 * 256;
  const float* v = a.vt[type] + khb * 64;
  float* Sout = khb ? a.So2[type] : a.So[type];
  int lane = tid & 63, w = tid >> 6, quad = lane >> 4, l16 = lane & 15;
  int d4 = tid & 63, rhi = tid >> 6;
  float4 h4 = ((const float4*)(a.Rf + (size_t)bi * 256))[d4];
  #pragma unroll
  for (int it = 0; it < 16; ++it) {
    int kl = it * 4 + rhi;                            // local row 0..63
    float4 w4 = ((const float4*)(W + (size_t)kl * 256))[d4];
    unsigned lo32 = cvt_pk_bf16(w4.x * h4.x, w4.y * h4.y);
    unsigned hi32 = cvt_pk_bf16(w4.z * h4.z, w4.w * h4.w);
    unsigned long long pk = (unsigned long long)lo32 | ((unsigned long long)hi32 << 32);
    int gphys = ((d4 >> 1) + kl) & 31;
    *(unsigned long long*)(w_lds + (size_t)kl * 256 + gphys * 8 + (d4 & 1) * 4) = pk;
  }
  BAR_LGKM();
  f32x4 acc[4][4];
  #pragma unroll
  for (int jj = 0; jj < 4; ++jj)
    #pragma unroll
    for (int c = 0; c < 4; ++c) acc[jj][c] = f32x4{0.f, 0.f, 0.f, 0.f};
  const unsigned short* Xp0 =
      Xhi + (size_t)(b * 256 + w * 4 * 16 + l16) * 256 + quad * 8;
  #pragma unroll 2
  for (int kc = 0; kc < 8; ++kc) {
    s16x8 af[4];
    #pragma unroll
    for (int c = 0; c < 4; ++c) {
      int krow = c * 16 + l16;
      int gp = (kc * 4 + quad + krow) & 31;
      af[c] = ldfrag(w_lds + (size_t)krow * 256 + gp * 8);
    }
    s16x8 bf[4];
    #pragma unroll
    for (int jj = 0; jj < 4; ++jj)
      bf[jj] = ldfrag(Xp0 + (size_t)jj * 16 * 256 + kc * 32);
    #pragma unroll
    for (int jj = 0; jj < 4; ++jj)
      #pragma unroll
      for (int c = 0; c < 4; ++c)
        acc[jj][c] = mfma16(af[c], bf[jj], acc[jj][c]);
  }
  float vv[4][4];
  #pragma unroll
  for (int c = 0; c < 4; ++c)
    #pragma unroll
    for (int r = 0; r < 4; ++r) vv[c][r] = v[c * 16 + quad * 4 + r];
  #pragma unroll
  for (int jj = 0; jj < 4; ++jj) {
    float s = 0.f;
    #pragma unroll
    for (int c = 0; c < 4; ++c)
      #pragma unroll
      for (int r = 0; r < 4; ++r) s += tanh_f(acc[jj][c][r]) * vv[c][r];
    s += __shfl_xor(s, 16);
    s += __shfl_xor(s, 32);
    int jt = w * 4 + jj;
    if (lane < 16) Sout[(size_t)bi * 256 + jt * 16 + l16] = s;
  }
}

// ---------------- scores cmb path (separate dispatch, grid 128) ---------------

struct ScCmbArgs {
  const float *Hc, *Rc, *Hm, *Rm, *HB, *hrf, *vcf, *vmf; float* S;
};

__global__ __launch_bounds__(256, 2) void k_sccmb(ScCmbArgs a) {
  int bi = blockIdx.x;
  int tid = threadIdx.x;
  __shared__ float rc_l[8 * 128];
  __shared__ float rm_l[8 * 128];
  __shared__ float hr_l[8 * 256];
  __shared__ float vc_l[128], vm_l[128];
  int b = bi >> 5, i0 = (bi & 31) << 3;       // 8 i-rows: gi0..gi0+7
  int gi0 = b * 256 + i0;
  {
    const float4* rc4 = (const float4*)(a.Rc + (size_t)gi0 * 128);
    const float4* rm4 = (const float4*)(a.Rm + (size_t)gi0 * 128);
    ((float4*)rc_l)[tid] = rc4[tid];
    ((float4*)rm_l)[tid] = rm4[tid];
    const float4* hr4 = (const float4*)(a.hrf + (size_t)gi0 * 256);
    ((float4*)hr_l)[tid] = hr4[tid];
    ((float4*)hr_l)[256 + tid] = hr4[256 + tid];
    if (tid < 128) { vc_l[tid] = a.vcf[tid]; vm_l[tid] = a.vmf[tid]; }
  }
  __syncthreads();
  int j = tid;
  size_t cb = (size_t)(b * 256 + j);
  float scq[8], smq[8], sbq[8];
  #pragma unroll
  for (int q = 0; q < 8; ++q) { scq[q] = 0.f; smq[q] = 0.f; sbq[q] = 0.f; }
  for (int k = 0; k < 128; ++k) {
    float hc = a.Hc[(size_t)k * M + cb];      // transposed: lane-consecutive
    float hm = a.Hm[(size_t)k * M + cb];
    float vck = vc_l[k], vmk = vm_l[k];
    #pragma unroll
    for (int q = 0; q < 8; ++q) {
      scq[q] += vck * tanh_f(hc + rc_l[q * 128 + k]);
      smq[q] += vmk * tanh_f(hm - rm_l[q * 128 + k]);
    }
  }
  for (int k = 0; k < 256; ++k) {
    float hb = a.HB[(size_t)k * M + cb];      // transposed
    #pragma unroll
    for (int q = 0; q < 8; ++q) sbq[q] += hb * hr_l[q * 256 + k];
  }
  #pragma unroll
  for (int q = 0; q < 8; ++q) {
    size_t o = (size_t)(gi0 + q) * 256 + j;
    a.S[(size_t)STY * 1 + o] = scq[q];
    a.S[(size_t)STY * 3 + o] = sbq[q];
    a.S[(size_t)STY * 4 + o] = smq[q];
  }
}

// ---------------- wsum with inline softmax (adds kh-half partials) ------------

__global__ __launch_bounds__(256) void k_wsum(const float* __restrict__ S,
    const float* __restrict__ S2,
    const float* __restrict__ hl_f, const float* __restrict__ hr_f,
    unsigned short* __restrict__ ahi, unsigned short* __restrict__ alo) {
  int it = blockIdx.x, type = blockIdx.y, b = blockIdx.z;
  __shared__ float p_l[8][256];
  __shared__ float red[4];
  int tid = threadIdx.x;
  for (int ii = 0; ii < 8; ++ii) {
    size_t idx = ((size_t)(b * 256 + it * 8 + ii)) * 256 + tid;
    float x = S[(size_t)type * STY + idx];
    if (type == 0) x += S2[idx];                        // pts partial (kh1)
    else if (type == 2) x += S2[(size_t)STY + idx];     // ptd partial (kh1)
    float m = x;
    for (int dl = 32; dl; dl >>= 1) m = fmaxf(m, __shfl_xor(m, dl));
    if ((tid & 63) == 0) red[tid >> 6] = m;
    __syncthreads();
    m = fmaxf(fmaxf(red[0], red[1]), fmaxf(red[2], red[3]));
    __syncthreads();
    float e = __expf(x - m);
    float sum = e;
    for (int dl = 32; dl; dl >>= 1) sum += __shfl_xor(sum, dl);
    if ((tid & 63) == 0) red[tid >> 6] = sum;
    __syncthreads();
    sum = red[0] + red[1] + red[2] + red[3];
    p_l[ii][tid] = e * rcp_f(sum);
    __syncthreads();
  }
  const float* src = (type == 0 ? hr_f : hl_f) + (size_t)b * 256 * 256;
  float acc[8] = {0.f, 0.f, 0.f, 0.f, 0.f, 0.f, 0.f, 0.f};
  for (int j = 0; j < 256; ++j) {
    float hv = src[(size_t)j * 256 + tid];
    #pragma unroll
    for (int ii = 0; ii < 8; ++ii) acc[ii] += p_l[ii][j] * hv;
  }
  int off = 256 * (1 + type);      // agg: [hr | pts | ptc | ptd | ptb | ptm]
  #pragma unroll
  for (int ii = 0; ii < 8; ++ii) {
    float vv = acc[ii];
    unsigned short hi = f2b(vv);
    size_t o = (size_t)(b * 256 + it * 8 + ii) * H12 + off + tid;
    ahi[o] = hi;
    alo[o] = f2b(vv - b2f(hi));
  }
}

// ---------------- fused tail ----------------

__global__ __launch_bounds__(256) void k_tail(const float* __restrict__ Hp,
    const float* __restrict__ hl_f, const float* __restrict__ vpf,
    const float* __restrict__ Wc2f, const float* __restrict__ Arc,
    const float* __restrict__ ar_f, const float* __restrict__ vcf,
    const float* __restrict__ Wpredf, float* __restrict__ out) {
  int b = blockIdx.x, tid = threadIdx.x;
  __shared__ float vl[128], wl[256], rvec[256], rlcl[128], red[4];
  if (tid < 128) vl[tid] = vpf[tid];
  __syncthreads();
  const float* hp = Hp + (size_t)(b * 256 + tid) * 128;
  float s = 0.f;
  for (int k = 0; k < 128; ++k) s += vl[k] * tanh_f(hp[k]);
  float m = s;
  for (int dl = 32; dl; dl >>= 1) m = fmaxf(m, __shfl_xor(m, dl));
  if ((tid & 63) == 0) red[tid >> 6] = m;
  __syncthreads();
  m = fmaxf(fmaxf(red[0], red[1]), fmaxf(red[2], red[3]));
  __syncthreads();
  float e = __expf(s - m);
  float sum = e;
  for (int dl = 32; dl; dl >>= 1) sum += __shfl_xor(sum, dl);
  if ((tid & 63) == 0) red[tid >> 6] = sum;
  __syncthreads();
  sum = red[0] + red[1] + red[2] + red[3];
  wl[tid] = e * rcp_f(sum);
  __syncthreads();
  float acc = 0.f;
  for (int t = 0; t < 256; ++t) acc += wl[t] * hl_f[(size_t)(b * 256 + t) * 256 + tid];
  rvec[tid] = acc;
  __syncthreads();
  if (tid < 128) {
    float a2 = 0.f;
    const float* wr = Wc2f + (size_t)tid * 256;
    for (int dk = 0; dk < 256; ++dk) a2 += rvec[dk] * wr[dk];
    rlcl[tid] = a2;
    vl[tid] = vcf[tid];
  }
  __syncthreads();
  const float* ap = Arc + (size_t)(b * 256 + tid) * 128;
  float s2 = 0.f;
  for (int k = 0; k < 128; ++k) s2 += vl[k] * (ap[k] + rlcl[k]);
  m = s2;
  for (int dl = 32; dl; dl >>= 1) m = fmaxf(m, __shfl_xor(m, dl));
  if ((tid & 63) == 0) red[tid >> 6] = m;
  __syncthreads();
  m = fmaxf(fmaxf(red[0], red[1]), fmaxf(red[2], red[3]));
  __syncthreads();
  float e2 = __expf(s2 - m);
  float sum2 = e2;
  for (int dl = 32; dl; dl >>= 1) sum2 += __shfl_xor(sum2, dl);
  if ((tid & 63) == 0) red[tid >> 6] = sum2;
  __syncthreads();
  sum2 = red[0] + red[1] + red[2] + red[3];
  wl[tid] = e2 * rcp_f(sum2);
  __syncthreads();
  float acc2 = 0.f;
  for (int t = 0; t < 256; ++t) acc2 += wl[t] * ar_f[(size_t)(b * 256 + t) * 256 + tid];
  rvec[tid] = acc2;
  __syncthreads();
  if (tid < 2) {
    float o = 0.f;
    const float* wp = Wpredf + (size_t)tid * 256;
    for (int dk = 0; dk < 256; ++dk) o += rvec[dk] * wp[dk];
    out[b * 2 + tid] = sigm(o);
  }
}

// ---------------- host ----------------

extern "C" void kernel_launch(void* const* d_in, const int* in_sizes, int n_in,
                              void* d_out, int out_size, void* d_ws, size_t ws_size,
                              hipStream_t stream) {
  (void)in_sizes; (void)n_in; (void)out_size; (void)ws_size;
  const int* inputs = (const int*)d_in[0];
  const float* embed = (const float*)d_in[1];
  const float* lWih = (const float*)d_in[2];
  const float* lWhh = (const float*)d_in[3];
  const float* lbih = (const float*)d_in[4];
  const float* lbhh = (const float*)d_in[5];
  const float* rWih = (const float*)d_in[6];
  const float* rWhh = (const float*)d_in[7];
  const float* rbih = (const float*)d_in[8];
  const float* rbhh = (const float*)d_in[9];
  const float* aWih = (const float*)d_in[10];
  const float* aWhh = (const float*)d_in[11];
  const float* abih = (const float*)d_in[12];
  const float* abhh = (const float*)d_in[13];
  const float* Wc1 = (const float*)d_in[14];
  const float* Wc2 = (const float*)d_in[15];
  const float* vc  = (const float*)d_in[16];
  const float* Wb  = (const float*)d_in[17];
  const float* Wd  = (const float*)d_in[18];
  const float* vd  = (const float*)d_in[19];
  const float* Wm  = (const float*)d_in[20];
  const float* vmv = (const float*)d_in[21];
  const float* Wsw = (const float*)d_in[22];
  const float* vsv = (const float*)d_in[23];
  const float* Wp  = (const float*)d_in[24];
  const float* vp  = (const float*)d_in[25];
  const float* Wpred = (const float*)d_in[26];

  char* ws = (char*)d_ws;
  size_t off = 0;
  auto alloc = [&](size_t bytes) -> void* {
    void* p = ws + off;
    off += (bytes + 255) & ~(size_t)255;
    return p;
  };
  unsigned short* xhi = (unsigned short*)alloc((size_t)M * EP * 2);
  unsigned short* xlo = (unsigned short*)alloc((size_t)M * EP * 2);
  unsigned short* wpad = (unsigned short*)alloc((size_t)4 * H3 * EP * 2);
  unsigned short* Whh_b = (unsigned short*)alloc((size_t)6 * H3 * H * 2);
  unsigned short* aWih_b = (unsigned short*)alloc((size_t)2 * H3 * H12 * 2);
  unsigned short* Wc1_b = (unsigned short*)alloc((size_t)H * H2 * 2);
  unsigned short* Wc2_b = (unsigned short*)alloc((size_t)H * H2 * 2);
  unsigned short* Wm_b  = (unsigned short*)alloc((size_t)H * H2 * 2);
  unsigned short* Wp_b  = (unsigned short*)alloc((size_t)H * H2 * 2);
  unsigned short* Wb_b  = (unsigned short*)alloc((size_t)H2 * H2 * 2);
  char* region1 = (char*)alloc((size_t)4 * M * H3 * 4);
  float* pre_lr = (float*)region1;
  float* S      = (float*)region1;
  float* pre_a  = (float*)region1;
  float* S2 = (float*)alloc((size_t)2 * STY * 4);   // kh1 partials: [pts | ptd]
  float* hl_f = (float*)alloc((size_t)M * H2 * 4);
  float* hr_f = (float*)alloc((size_t)M * H2 * 4);
  unsigned short* hl_hi = (unsigned short*)alloc((size_t)M * H2 * 2);
  unsigned short* hl_lo = (unsigned short*)alloc((size_t)M * H2 * 2);
  unsigned short* hr_hi = (unsigned short*)alloc((size_t)M * H2 * 2);
  unsigned short* hr_lo = (unsigned short*)alloc((size_t)M * H2 * 2);
  float* Hc = (float*)alloc((size_t)M * H * 4);     // transposed [H][M]
  float* Rc = (float*)alloc((size_t)M * H * 4);
  float* Hm = (float*)alloc((size_t)M * H * 4);     // transposed [H][M]
  float* Rm = (float*)alloc((size_t)M * H * 4);
  float* Hp = (float*)alloc((size_t)M * H * 4);
  float* HB = (float*)alloc((size_t)M * H2 * 4);    // transposed [H2][M]
  unsigned short* agg_hi = (unsigned short*)alloc((size_t)M * H12 * 2);
  unsigned short* agg_lo = (unsigned short*)alloc((size_t)M * H12 * 2);
  float* ar_f = (float*)alloc((size_t)M * H2 * 4);
  unsigned short* ar_hi = (unsigned short*)alloc((size_t)M * H2 * 2);
  unsigned short* ar_lo = (unsigned short*)alloc((size_t)M * H2 * 2);
  float* Arc = (float*)alloc((size_t)M * H * 4);

  // 1. staging
  StageArgs sa{};
  sa.cs[0] = lWhh;  sa.cd[0] = Whh_b;                 sa.cn[0] = 2 * H3 * H;
  sa.cs[1] = rWhh;  sa.cd[1] = Whh_b + 2 * H3 * H;    sa.cn[1] = 2 * H3 * H;
  sa.cs[2] = aWhh;  sa.cd[2] = Whh_b + 4 * H3 * H;    sa.cn[2] = 2 * H3 * H;
  sa.cs[3] = aWih;  sa.cd[3] = aWih_b;                sa.cn[3] = 2 * H3 * H12;
  sa.cs[4] = Wc1;   sa.cd[4] = Wc1_b;                 sa.cn[4] = H * H2;
  sa.cs[5] = Wc2;   sa.cd[5] = Wc2_b;                 sa.cn[5] = H * H2;
  sa.cs[6] = Wm;    sa.cd[6] = Wm_b;                  sa.cn[6] = H * H2;
  sa.cs[7] = Wp;    sa.cd[7] = Wp_b;                  sa.cn[7] = H * H2;
  sa.cs[8] = Wb;    sa.cd[8] = Wb_b;                  sa.cn[8] = H2 * H2;
  sa.idx = inputs; sa.emb = embed; sa.xhi = xhi; sa.xlo = xlo;
  sa.lW = lWih; sa.rW = rWih; sa.wpad = wpad;
  k_stage<<<dim3((2 * H3 * H12 + 255) / 256, 11), dim3(256), 0, stream>>>(sa);

  // 2. input projections for l/r GRUs
  GemmBatch ga{};
  const float* biases[4] = { lbih, lbih + H3, rbih, rbih + H3 };
  for (int u = 0; u < 4; ++u)
    ga.d[u] = GemmDesc{ xhi, xlo, wpad + (size_t)u * H3 * EP, biases[u],
                        pre_lr + (size_t)u * M * H3, H3, EP, 0 };
  k_gemm<<<dim3(16, 6, 4), dim3(256), 0, stream>>>(ga);

  // 3. l/r recurrences (writes fp32 + hi/lo + agg hr-copy); 1 unit per block
  RecArgs r1{};
  r1.whh[0] = Whh_b;               r1.whh[1] = Whh_b + H3 * H;
  r1.whh[2] = Whh_b + 2 * H3 * H;  r1.whh[3] = Whh_b + 3 * H3 * H;
  for (int u = 0; u < 4; ++u) r1.pre[u] = pre_lr + (size_t)u * M * H3;
  r1.outf[0] = r1.outf[1] = hl_f; r1.outf[2] = r1.outf[3] = hr_f;
  r1.outhi[0] = r1.outhi[1] = hl_hi; r1.outhi[2] = r1.outhi[3] = hr_hi;
  r1.outlo[0] = r1.outlo[1] = hl_lo; r1.outlo[2] = r1.outlo[3] = hr_lo;
  r1.agghi[0] = r1.agghi[1] = nullptr; r1.agghi[2] = r1.agghi[3] = agg_hi;
  r1.agglo[0] = r1.agglo[1] = nullptr; r1.agglo[2] = r1.agglo[3] = agg_lo;
  r1.bhh[0] = lbhh; r1.bhh[1] = lbhh + H3; r1.bhh[2] = rbhh; r1.bhh[3] = rbhh + H3;
  r1.colOff[0] = 0; r1.colOff[1] = H; r1.colOff[2] = 0; r1.colOff[3] = H;
  r1.dir[0] = 0; r1.dir[1] = 1; r1.dir[2] = 0; r1.dir[3] = 1;
  k_gru<<<dim3(4), dim3(512), 0, stream>>>(r1);

  // 4. projection GEMMs (Hc/Hm/HB transposed for the j-streamed cmb path)
  GemmBatch gbB{};
  gbB.d[0] = GemmDesc{ hl_hi, hl_lo, Wc1_b, nullptr, Hc, H, H2, 1 };
  gbB.d[1] = GemmDesc{ hr_hi, hr_lo, Wc2_b, nullptr, Rc, H, H2, 0 };
  gbB.d[2] = GemmDesc{ hl_hi, hl_lo, Wm_b, nullptr, Hm, H, H2, 1 };
  gbB.d[3] = GemmDesc{ hr_hi, hr_lo, Wm_b, nullptr, Rm, H, H2, 0 };
  gbB.d[4] = GemmDesc{ hl_hi, hl_lo, Wb_b, nullptr, HB, H2, H2, 1 };
  gbB.d[5] = GemmDesc{ hl_hi, hl_lo, Wp_b, nullptr, Hp, H, H2, 0 };
  k_gemm<<<dim3(16, 4, 6), dim3(256), 0, stream>>>(gbB);

  // 5a. MFMA scores (pts/ptd halves)
  ScMMArgs sm{};
  sm.Xhi[0] = hl_hi; sm.Wt[0] = Wd;  sm.vt[0] = vd;  sm.So[0] = S + (size_t)2 * STY;
  sm.Xhi[1] = hr_hi; sm.Wt[1] = Wsw; sm.vt[1] = vsv; sm.So[1] = S + (size_t)0 * STY;
  sm.So2[0] = S2 + (size_t)STY;   // ptd kh1 partial
  sm.So2[1] = S2;                 // pts kh1 partial
  sm.Rf = hr_f;
  k_scmm<<<dim3(M, 4), dim3(256), 0, stream>>>(sm);

  // 5b. combined ptc/ptb/ptm scores
  ScCmbArgs scb{};
  scb.Hc = Hc; scb.Rc = Rc; scb.Hm = Hm; scb.Rm = Rm; scb.HB = HB;
  scb.hrf = hr_f; scb.vcf = vc; scb.vmf = vmv; scb.S = S;
  k_sccmb<<<dim3(128), dim3(256), 0, stream>>>(scb);

  // 6. softmax + weighted sums into agg
  k_wsum<<<dim3(32, 5, 4), dim3(256), 0, stream>>>(S, S2, hl_f, hr_f, agg_hi, agg_lo);

  // 7. agg GRU input projection
  GemmBatch gc{};
  gc.d[0] = GemmDesc{ agg_hi, agg_lo, aWih_b, abih, pre_a, H3, H12, 0 };
  gc.d[1] = GemmDesc{ agg_hi, agg_lo, aWih_b + (size_t)H3 * H12, abih + H3,
                      pre_a + (size_t)M * H3, H3, H12, 0 };
  k_gemm<<<dim3(16, 6, 2), dim3(256), 0, stream>>>(gc);

  // 8. agg recurrence (writes ar fp32 + hi/lo); 1 unit per block
  RecArgs r2{};
  r2.whh[0] = Whh_b + 4 * H3 * H; r2.whh[1] = Whh_b + 5 * H3 * H;
  r2.whh[2] = r2.whh[3] = Whh_b + 4 * H3 * H;
  r2.pre[0] = pre_a; r2.pre[1] = pre_a + (size_t)M * H3;
  r2.pre[2] = r2.pre[3] = pre_a;
  r2.outf[0] = r2.outf[1] = r2.outf[2] = r2.outf[3] = ar_f;
  r2.outhi[0] = r2.outhi[1] = r2.outhi[2] = r2.outhi[3] = ar_hi;
  r2.outlo[0] = r2.outlo[1] = r2.outlo[2] = r2.outlo[3] = ar_lo;
  for (int u = 0; u < 4; ++u) { r2.agghi[u] = nullptr; r2.agglo[u] = nullptr; }
  r2.bhh[0] = abhh; r2.bhh[1] = abhh + H3; r2.bhh[2] = r2.bhh[3] = abhh;
  r2.colOff[0] = 0; r2.colOff[1] = H; r2.colOff[2] = r2.colOff[3] = 0;
  r2.dir[0] = 0; r2.dir[1] = 1; r2.dir[2] = r2.dir[3] = 0;
  k_gru<<<dim3(2), dim3(512), 0, stream>>>(r2);

  // 9. Arc GEMM
  GemmBatch gd{};
  gd.d[0] = GemmDesc{ ar_hi, ar_lo, Wc1_b, nullptr, Arc, H, H2, 0 };
  k_gemm<<<dim3(16, 2, 1), dim3(256), 0, stream>>>(gd);

  // 10. fused tail
  k_tail<<<dim3(4), dim3(256), 0, stream>>>(Hp, hl_f, vp, Wc2, Arc, ar_f, vc, Wpred,
                                            (float*)d_out);
}

// Round 9
// 687.322 us; speedup vs baseline: 1.0888x; 1.0475x over previous
//
#include <hip/hip_runtime.h>

// MANNet forward, MI355X gfx950. Inputs fp32 (+int32 ids), output fp32.
// R18: three independent bit-exact cuts.
// (1) k_gru: hi/lo split via v_cvt_pk_bf16_f32 (RNE, proven bit-identical to the
//     manual f2b in R12) — 10 ops -> 4 on the per-step h-critical path.
// (2) k_stage: flattened 1D grid (9728 blocks vs 50688, ~41k empty WG dispatches
//     removed; per-seg prefix offsets in args).
// (3) k_sccmb: 4 i-rows/block, grid 256 (was 8 rows/128 blocks, half GPU idle on
//     a tanh-issue-heavy kernel).

#define DEV static __device__ __forceinline__
#define BAR_LGKM() __asm__ volatile("s_waitcnt lgkmcnt(0)\ns_barrier" ::: "memory")

typedef __attribute__((ext_vector_type(4))) float f32x4;
typedef __attribute__((ext_vector_type(8))) short s16x8;
typedef __attribute__((ext_vector_type(4))) unsigned int u32x4;
typedef __attribute__((ext_vector_type(2))) unsigned int u32x2;

constexpr int T = 256, E = 300, EP = 320, H = 128, H2 = 256, H3 = 384, H12 = 1536;
constexpr int M = 1024;            // B*T
constexpr int STY = 262144;        // 4*T*T elements per score type

DEV float b2f(unsigned short h) { return __uint_as_float(((unsigned)h) << 16); }
DEV unsigned short f2b(float f) {
  unsigned u = __float_as_uint(f);
  u += 0x7fff + ((u >> 16) & 1);            // RNE
  return (unsigned short)(u >> 16);
}
DEV unsigned cvt_pk_bf16(float lo, float hi) {   // dst = {bf16(lo), bf16(hi)} RNE
  unsigned r;
  __asm__("v_cvt_pk_bf16_f32 %0, %1, %2" : "=v"(r) : "v"(lo), "v"(hi));
  return r;
}
DEV float rcp_f(float x) {                       // v_rcp_f32: 1 ulp, 1 trans op
  float r;
  __asm__("v_rcp_f32 %0, %1" : "=v"(r) : "v"(x));
  return r;
}
DEV float sigm(float x) { return rcp_f(1.f + __expf(-x)); }
DEV float tanh_f(float x) {
  float e = __expf(2.f * x);
  return __builtin_fmaf(-2.f, rcp_f(e + 1.f), 1.f);
}
// lanes 0-31 <- x0, lanes 32-63 <- x1's lanes 0-31 (one v_permlane32_swap_b32)
DEV float plsel(float x0, float x1) {
  u32x2 r = __builtin_amdgcn_permlane32_swap(
      __float_as_uint(x0), __float_as_uint(x1), false, false);
  return __uint_as_float(r[0]);
}

DEV s16x8 ldfrag(const unsigned short* p) {
  u32x4 v = *(const u32x4*)p;
  return __builtin_bit_cast(s16x8, v);
}
DEV f32x4 mfma16(s16x8 a, s16x8 b, f32x4 c) {
  return __builtin_amdgcn_mfma_f32_16x16x32_bf16(a, b, c, 0, 0, 0);
}

// ---------------- fused staging: 9x cvt + embed + padw (flattened grid) -------

struct StageArgs {
  const float* cs[9]; unsigned short* cd[9]; int cn[9];
  const int* idx; const float* emb; unsigned short* xhi; unsigned short* xlo;
  const float* lW; const float* rW; unsigned short* wpad;
  int bo[12];                      // per-seg block offsets; bo[11] = total
};

__global__ void k_stage(StageArgs sa) {
  int blk = blockIdx.x;
  int seg = 0;
  #pragma unroll
  for (int s2 = 1; s2 < 11; ++s2) seg = (blk >= sa.bo[s2]) ? s2 : seg;
  int i = (blk - sa.bo[seg]) * 256 + threadIdx.x;
  if (seg < 9) {
    if (i < sa.cn[seg]) sa.cd[seg][i] = f2b(sa.cs[seg][i]);
    return;
  }
  if (seg == 9) {
    if (i >= M * EP) return;
    int m = i / EP, e = i - m * EP;
    int r = sa.idx[m];
    float v = (e < E) ? sa.emb[(size_t)r * E + e] : 0.f;
    unsigned short hi = f2b(v);
    sa.xhi[i] = hi;
    sa.xlo[i] = f2b(v - b2f(hi));
    return;
  }
  if (i >= 4 * H3 * EP) return;
  int e = i % EP, n = (i / EP) % H3, uu = i / (EP * H3);
  const float* src = (uu < 2 ? sa.lW : sa.rW) + (size_t)((uu & 1) * H3 + n) * E;
  sa.wpad[i] = (e < E) ? f2b(src[e]) : (unsigned short)0;
}

// ---------------- generic GEMM: C = (Ahi+Alo) @ W^T (+bias), fp32 out ----------
// tr=1: write transposed C_t[n*M + m] (for j-streamed consumers).

struct GemmDesc {
  const unsigned short* Ahi; const unsigned short* Alo; const unsigned short* W;
  const float* bias; float* Cf; int N; int K; int tr;
};
struct GemmBatch { GemmDesc d[8]; };

__global__ __launch_bounds__(256) void k_gemm(GemmBatch gb) {
  GemmDesc g = gb.d[blockIdx.z];
  int nb = blockIdx.y * 64;
  if (nb >= g.N) return;
  int mb = blockIdx.x * 64;
  int lane = threadIdx.x & 63, w = threadIdx.x >> 6, quad = lane >> 4, l16 = lane & 15;
  int K = g.K;
  const unsigned short* Ahp = g.Ahi + (size_t)(mb + w * 16 + l16) * K + quad * 8;
  const unsigned short* Alp = g.Alo + (size_t)(mb + w * 16 + l16) * K + quad * 8;
  const unsigned short* Wp = g.W + (size_t)(nb + l16) * K + quad * 8;
  f32x4 acc[4];
  #pragma unroll
  for (int nt = 0; nt < 4; ++nt) acc[nt] = f32x4{0.f, 0.f, 0.f, 0.f};
  for (int k = 0; k < K; k += 32) {
    s16x8 ah = ldfrag(Ahp + k);
    s16x8 al = ldfrag(Alp + k);
    #pragma unroll
    for (int nt = 0; nt < 4; ++nt) {
      s16x8 b = ldfrag(Wp + (size_t)nt * 16 * K + k);
      acc[nt] = mfma16(ah, b, acc[nt]);
      acc[nt] = mfma16(al, b, acc[nt]);
    }
  }
  int mr0 = mb + w * 16 + quad * 4;
  #pragma unroll
  for (int nt = 0; nt < 4; ++nt) {
    int col = nb + nt * 16 + l16;
    float bv = g.bias ? g.bias[col] : 0.f;
    #pragma unroll
    for (int r = 0; r < 4; ++r) {
      if (g.tr)
        g.Cf[(size_t)col * M + (mr0 + r)] = acc[nt][r] + bv;
      else
        g.Cf[(size_t)(mr0 + r) * g.N + col] = acc[nt][r] + bv;
    }
  }
}

// ---------------- GRU recurrence v7 ----------------

struct RecArgs {
  const unsigned short* whh[4];
  const float* pre[4];
  float* outf[4];
  unsigned short* outhi[4];
  unsigned short* outlo[4];
  unsigned short* agghi[4];      // null -> no agg copy
  unsigned short* agglo[4];
  const float* bhh[4];
  int colOff[4];
  int dir[4];
};

// One recurrence step. pr_/pz_/pn_ are this step's pre-activations (bh_r/bh_z
// pre-added); they are refreshed from pq_ (advanced 2 steps) for step s+2.
#define GRU_STEP(pr_, pz_, pn_, pq_, hcur_, hnxt_, s_)                         \
  {                                                                            \
    float pr = pr_, pz = pz_, pn = pn_;                                        \
    pq_ += pst2;                                                               \
    pr_ = pq_[0] + bh_r; pz_ = pq_[128] + bh_z; pn_ = pq_[256];                \
    const unsigned short* hb_ = hcur_ + l16 * 136 + quad * 8;                  \
    s16x8 ah0 = ldfrag(hb_);                                                   \
    s16x8 ah1 = ldfrag(hb_ + 32);                                              \
    s16x8 ah2 = ldfrag(hb_ + 64);                                              \
    s16x8 ah3 = ldfrag(hb_ + 96);                                              \
    f32x4 z4 = f32x4{0.f, 0.f, 0.f, 0.f};                                      \
    f32x4 aR0 = mfma16(ah0, bq[0][0], z4);                                     \
    f32x4 aR1 = mfma16(ah2, bq[0][2], z4);                                     \
    aR0 = mfma16(ah1, bq[0][1], aR0);                                          \
    aR1 = mfma16(ah3, bq[0][3], aR1);                                          \
    f32x4 aZ0 = mfma16(ah0, bq[1][0], z4);                                     \
    f32x4 aZ1 = mfma16(ah2, bq[1][2], z4);                                     \
    aZ0 = mfma16(ah1, bq[1][1], aZ0);                                          \
    aZ1 = mfma16(ah3, bq[1][3], aZ1);                                          \
    float r0 = (aR0[0] + aR1[0]) + (aR0[1] + aR1[1]);                          \
    float r1v = (aR0[2] + aR1[2]) + (aR0[3] + aR1[3]);                         \
    float rg = sigm(pr + plsel(r0, r1v));                                      \
    f32x4 aN0 = mfma16(ah0, bq[2][0], z4);                                     \
    f32x4 aN1 = mfma16(ah2, bq[2][2], z4);                                     \
    aN0 = mfma16(ah1, bq[2][1], aN0);                                          \
    aN1 = mfma16(ah3, bq[2][3], aN1);                                          \
    float z0 = (aZ0[0] + aZ1[0]) + (aZ0[1] + aZ1[1]);                          \
    float z1 = (aZ0[2] + aZ1[2]) + (aZ0[3] + aZ1[3]);                          \
    float zg = sigm(pz + plsel(z0, z1));                                       \
    float n0 = (aN0[0] + aN1[0]) + (aN0[1] + aN1[1]);                          \
    float n1 = (aN0[2] + aN1[2]) + (aN0[3] + aN1[3]);                          \
    float ng = tanh_f(pn + rg * (plsel(n0, n1) + bh_n));                       \
    hf = __builtin_fmaf(zg, hf - ng, ng);                                      \
    unsigned hp32 = cvt_pk_bf16(hf, hf);                                       \
    float rem = hf - __uint_as_float(hp32 << 16);                              \
    unsigned lp32 = cvt_pk_bf16(rem, rem);                                     \
    unsigned short hi = (unsigned short)hp32;                                  \
    unsigned short lo = (unsigned short)lp32;                                  \
    hnxt_[(2 * b) * 136 + d] = hi;                                             \
    hnxt_[(2 * b + 1) * 136 + d] = lo;                                         \
    int tq = dir ? (T - 1 - (s_)) : (s_);                                      \
    size_t o_ = (size_t)(b * T + tq) * H2 + colOff + d;                        \
    outf[o_] = hf; outhi[o_] = hi; outlo[o_] = lo;                             \
    if (agghi) {                                                               \
      size_t a_ = (size_t)(b * T + tq) * H12 + colOff + d;                     \
      agghi[a_] = hi; agglo[a_] = lo;                                          \
    }                                                                          \
    BAR_LGKM();                                                                \
  }

__global__ __launch_bounds__(512) void k_gru(RecArgs ra) {
  int u = blockIdx.x;
  __shared__ __align__(16) unsigned short hs[2][16 * 136];
  int tid = threadIdx.x, lane = tid & 63, w8 = tid >> 6;
  int quad = lane >> 4, l16 = lane & 15;
  for (int i = tid; i < 2 * 16 * 136; i += 512) ((unsigned short*)hs)[i] = 0;
  const unsigned short* whh = ra.whh[u];
  s16x8 bq[3][4];
  #pragma unroll
  for (int g = 0; g < 3; ++g) {
    int row = g * 128 + w8 * 16 + l16;
    #pragma unroll
    for (int kc = 0; kc < 4; ++kc)
      bq[g][kc] = ldfrag(whh + (size_t)row * H + kc * 32 + quad * 8);
  }
  const float* bhh = ra.bhh[u];
  const float* pre = ra.pre[u];
  float* outf = ra.outf[u];
  unsigned short* outhi = ra.outhi[u];
  unsigned short* outlo = ra.outlo[u];
  unsigned short* agghi = ra.agghi[u];
  unsigned short* agglo = ra.agglo[u];
  int colOff = ra.colOff[u], dir = ra.dir[u];
  int b = ((quad & 1) << 1) | (quad >> 1);
  int d = w8 * 16 + l16;
  float bh_r = bhh[d], bh_z = bhh[d + 128], bh_n = bhh[d + 256];
  float hf = 0.f;
  int t0 = dir ? (T - 1) : 0;
  long pst = dir ? -(long)H3 : (long)H3;
  long pst2 = 2 * pst;
  // depth-2 prefetch: even/odd register pairs. Final iterations overrun the
  // unit's pre slab by <=2 rows (3KB) — lands in adjacent ws regions, unused.
  const float* pqE = pre + (size_t)(b * T + t0) * H3 + d;
  const float* pqO = pqE + pst;
  float e_pr = pqE[0] + bh_r, e_pz = pqE[128] + bh_z, e_pn = pqE[256];
  float o_pr = pqO[0] + bh_r, o_pz = pqO[128] + bh_z, o_pn = pqO[256];
  __syncthreads();
  for (int s = 0; s < T; s += 2) {
    GRU_STEP(e_pr, e_pz, e_pn, pqE, hs[0], hs[1], s);
    GRU_STEP(o_pr, o_pz, o_pn, pqO, hs[1], hs[0], s + 1);
  }
}

// ---------------- scores MFMA path (kc-outer, transient fragments) ------------

struct ScMMArgs {
  const unsigned short* Xhi[2];
  const float* Rf; const float* Wt[2]; const float* vt[2];
  float* So[2]; float* So2[2];
};

__global__ __launch_bounds__(256, 2) void k_scmm(ScMMArgs a) {
  __shared__ __align__(16) unsigned short w_lds[64 * 256];   // 32KB swizzled bf16
  int which = blockIdx.y;
  int bi = blockIdx.x, b = bi >> 8;
  int tid = threadIdx.x;
  int type = which >> 1, khb = which & 1;
  const unsigned short* Xhi = a.Xhi[type];
  const float* W = a.Wt[type] + (size_t)khb * 64 * 256;
  const float* v = a.vt[type] + khb * 64;
  float* Sout = khb ? a.So2[type] : a.So[type];
  int lane = tid & 63, w = tid >> 6, quad = lane >> 4, l16 = lane & 15;
  int d4 = tid & 63, rhi = tid >> 6;
  float4 h4 = ((const float4*)(a.Rf + (size_t)bi * 256))[d4];
  #pragma unroll
  for (int it = 0; it < 16; ++it) {
    int kl = it * 4 + rhi;                            // local row 0..63
    float4 w4 = ((const float4*)(W + (size_t)kl * 256))[d4];
    unsigned lo32 = cvt_pk_bf16(w4.x * h4.x, w4.y * h4.y);
    unsigned hi32 = cvt_pk_bf16(w4.z * h4.z, w4.w * h4.w);
    unsigned long long pk = (unsigned long long)lo32 | ((unsigned long long)hi32 << 32);
    int gphys = ((d4 >> 1) + kl) & 31;
    *(unsigned long long*)(w_lds + (size_t)kl * 256 + gphys * 8 + (d4 & 1) * 4) = pk;
  }
  BAR_LGKM();
  f32x4 acc[4][4];
  #pragma unroll
  for (int jj = 0; jj < 4; ++jj)
    #pragma unroll
    for (int c = 0; c < 4; ++c) acc[jj][c] = f32x4{0.f, 0.f, 0.f, 0.f};
  const unsigned short* Xp0 =
      Xhi + (size_t)(b * 256 + w * 4 * 16 + l16) * 256 + quad * 8;
  #pragma unroll 2
  for (int kc = 0; kc < 8; ++kc) {
    s16x8 af[4];
    #pragma unroll
    for (int c = 0; c < 4; ++c) {
      int krow = c * 16 + l16;
      int gp = (kc * 4 + quad + krow) & 31;
      af[c] = ldfrag(w_lds + (size_t)krow * 256 + gp * 8);
    }
    s16x8 bf[4];
    #pragma unroll
    for (int jj = 0; jj < 4; ++jj)
      bf[jj] = ldfrag(Xp0 + (size_t)jj * 16 * 256 + kc * 32);
    #pragma unroll
    for (int jj = 0; jj < 4; ++jj)
      #pragma unroll
      for (int c = 0; c < 4; ++c)
        acc[jj][c] = mfma16(af[c], bf[jj], acc[jj][c]);
  }
  float vv[4][4];
  #pragma unroll
  for (int c = 0; c < 4; ++c)
    #pragma unroll
    for (int r = 0; r < 4; ++r) vv[c][r] = v[c * 16 + quad * 4 + r];
  #pragma unroll
  for (int jj = 0; jj < 4; ++jj) {
    float s = 0.f;
    #pragma unroll
    for (int c = 0; c < 4; ++c)
      #pragma unroll
      for (int r = 0; r < 4; ++r) s += tanh_f(acc[jj][c][r]) * vv[c][r];
    s += __shfl_xor(s, 16);
    s += __shfl_xor(s, 32);
    int jt = w * 4 + jj;
    if (lane < 16) Sout[(size_t)bi * 256 + jt * 16 + l16] = s;
  }
}

// ---------------- scores cmb path (grid 256, 4 i-rows/block) ------------------

struct ScCmbArgs {
  const float *Hc, *Rc, *Hm, *Rm, *HB, *hrf, *vcf, *vmf; float* S;
};

__global__ __launch_bounds__(256, 2) void k_sccmb(ScCmbArgs a) {
  int bi = blockIdx.x;
  int tid = threadIdx.x;
  __shared__ float rc_l[4 * 128];
  __shared__ float rm_l[4 * 128];
  __shared__ float hr_l[4 * 256];
  __shared__ float vc_l[128], vm_l[128];
  int b = bi >> 6, i0 = (bi & 63) << 2;       // 4 i-rows: gi0..gi0+3
  int gi0 = b * 256 + i0;
  {
    const float4* hr4 = (const float4*)(a.hrf + (size_t)gi0 * 256);
    ((float4*)hr_l)[tid] = hr4[tid];
    if (tid < 128) {
      const float4* rc4 = (const float4*)(a.Rc + (size_t)gi0 * 128);
      const float4* rm4 = (const float4*)(a.Rm + (size_t)gi0 * 128);
      ((float4*)rc_l)[tid] = rc4[tid];
      ((float4*)rm_l)[tid] = rm4[tid];
      vc_l[tid] = a.vcf[tid]; vm_l[tid] = a.vmf[tid];
    }
  }
  __syncthreads();
  int j = tid;
  size_t cb = (size_t)(b * 256 + j);
  float scq[4], smq[4], sbq[4];
  #pragma unroll
  for (int q = 0; q < 4; ++q) { scq[q] = 0.f; smq[q] = 0.f; sbq[q] = 0.f; }
  for (int k = 0; k < 128; ++k) {
    float hc = a.Hc[(size_t)k * M + cb];      // transposed: lane-consecutive
    float hm = a.Hm[(size_t)k * M + cb];
    float vck = vc_l[k], vmk = vm_l[k];
    #pragma unroll
    for (int q = 0; q < 4; ++q) {
      scq[q] += vck * tanh_f(hc + rc_l[q * 128 + k]);
      smq[q] += vmk * tanh_f(hm - rm_l[q * 128 + k]);
    }
  }
  for (int k = 0; k < 256; ++k) {
    float hb = a.HB[(size_t)k * M + cb];      // transposed
    #pragma unroll
    for (int q = 0; q < 4; ++q) sbq[q] += hb * hr_l[q * 256 + k];
  }
  #pragma unroll
  for (int q = 0; q < 4; ++q) {
    size_t o = (size_t)(gi0 + q) * 256 + j;
    a.S[(size_t)STY * 1 + o] = scq[q];
    a.S[(size_t)STY * 3 + o] = sbq[q];
    a.S[(size_t)STY * 4 + o] = smq[q];
  }
}

// ---------------- wsum with inline softmax (adds kh-half partials) ------------

__global__ __launch_bounds__(256) void k_wsum(const float* __restrict__ S,
    const float* __restrict__ S2,
    const float* __restrict__ hl_f, const float* __restrict__ hr_f,
    unsigned short* __restrict__ ahi, unsigned short* __restrict__ alo) {
  int it = blockIdx.x, type = blockIdx.y, b = blockIdx.z;
  __shared__ float p_l[8][256];
  __shared__ float red[4];
  int tid = threadIdx.x;
  for (int ii = 0; ii < 8; ++ii) {
    size_t idx = ((size_t)(b * 256 + it * 8 + ii)) * 256 + tid;
    float x = S[(size_t)type * STY + idx];
    if (type == 0) x += S2[idx];                        // pts partial (kh1)
    else if (type == 2) x += S2[(size_t)STY + idx];     // ptd partial (kh1)
    float m = x;
    for (int dl = 32; dl; dl >>= 1) m = fmaxf(m, __shfl_xor(m, dl));
    if ((tid & 63) == 0) red[tid >> 6] = m;
    __syncthreads();
    m = fmaxf(fmaxf(red[0], red[1]), fmaxf(red[2], red[3]));
    __syncthreads();
    float e = __expf(x - m);
    float sum = e;
    for (int dl = 32; dl; dl >>= 1) sum += __shfl_xor(sum, dl);
    if ((tid & 63) == 0) red[tid >> 6] = sum;
    __syncthreads();
    sum = red[0] + red[1] + red[2] + red[3];
    p_l[ii][tid] = e * rcp_f(sum);
    __syncthreads();
  }
  const float* src = (type == 0 ? hr_f : hl_f) + (size_t)b * 256 * 256;
  float acc[8] = {0.f, 0.f, 0.f, 0.f, 0.f, 0.f, 0.f, 0.f};
  for (int j = 0; j < 256; ++j) {
    float hv = src[(size_t)j * 256 + tid];
    #pragma unroll
    for (int ii = 0; ii < 8; ++ii) acc[ii] += p_l[ii][j] * hv;
  }
  int off = 256 * (1 + type);      // agg: [hr | pts | ptc | ptd | ptb | ptm]
  #pragma unroll
  for (int ii = 0; ii < 8; ++ii) {
    float vv = acc[ii];
    unsigned short hi = f2b(vv);
    size_t o = (size_t)(b * 256 + it * 8 + ii) * H12 + off + tid;
    ahi[o] = hi;
    alo[o] = f2b(vv - b2f(hi));
  }
}

// ---------------- fused tail ----------------

__global__ __launch_bounds__(256) void k_tail(const float* __restrict__ Hp,
    const float* __restrict__ hl_f, const float* __restrict__ vpf,
    const float* __restrict__ Wc2f, const float* __restrict__ Arc,
    const float* __restrict__ ar_f, const float* __restrict__ vcf,
    const float* __restrict__ Wpredf, float* __restrict__ out) {
  int b = blockIdx.x, tid = threadIdx.x;
  __shared__ float vl[128], wl[256], rvec[256], rlcl[128], red[4];
  if (tid < 128) vl[tid] = vpf[tid];
  __syncthreads();
  const float* hp = Hp + (size_t)(b * 256 + tid) * 128;
  float s = 0.f;
  for (int k = 0; k < 128; ++k) s += vl[k] * tanh_f(hp[k]);
  float m = s;
  for (int dl = 32; dl; dl >>= 1) m = fmaxf(m, __shfl_xor(m, dl));
  if ((tid & 63) == 0) red[tid >> 6] = m;
  __syncthreads();
  m = fmaxf(fmaxf(red[0], red[1]), fmaxf(red[2], red[3]));
  __syncthreads();
  float e = __expf(s - m);
  float sum = e;
  for (int dl = 32; dl; dl >>= 1) sum += __shfl_xor(sum, dl);
  if ((tid & 63) == 0) red[tid >> 6] = sum;
  __syncthreads();
  sum = red[0] + red[1] + red[2] + red[3];
  wl[tid] = e * rcp_f(sum);
  __syncthreads();
  float acc = 0.f;
  for (int t = 0; t < 256; ++t) acc += wl[t] * hl_f[(size_t)(b * 256 + t) * 256 + tid];
  rvec[tid] = acc;
  __syncthreads();
  if (tid < 128) {
    float a2 = 0.f;
    const float* wr = Wc2f + (size_t)tid * 256;
    for (int dk = 0; dk < 256; ++dk) a2 += rvec[dk] * wr[dk];
    rlcl[tid] = a2;
    vl[tid] = vcf[tid];
  }
  __syncthreads();
  const float* ap = Arc + (size_t)(b * 256 + tid) * 128;
  float s2 = 0.f;
  for (int k = 0; k < 128; ++k) s2 += vl[k] * (ap[k] + rlcl[k]);
  m = s2;
  for (int dl = 32; dl; dl >>= 1) m = fmaxf(m, __shfl_xor(m, dl));
  if ((tid & 63) == 0) red[tid >> 6] = m;
  __syncthreads();
  m = fmaxf(fmaxf(red[0], red[1]), fmaxf(red[2], red[3]));
  __syncthreads();
  float e2 = __expf(s2 - m);
  float sum2 = e2;
  for (int dl = 32; dl; dl >>= 1) sum2 += __shfl_xor(sum2, dl);
  if ((tid & 63) == 0) red[tid >> 6] = sum2;
  __syncthreads();
  sum2 = red[0] + red[1] + red[2] + red[3];
  wl[tid] = e2 * rcp_f(sum2);
  __syncthreads();
  float acc2 = 0.f;
  for (int t = 0; t < 256; ++t) acc2 += wl[t] * ar_f[(size_t)(b * 256 + t) * 256 + tid];
  rvec[tid] = acc2;
  __syncthreads();
  if (tid < 2) {
    float o = 0.f;
    const float* wp = Wpredf + (size_t)tid * 256;
    for (int dk = 0; dk < 256; ++dk) o += rvec[dk] * wp[dk];
    out[b * 2 + tid] = sigm(o);
  }
}

// ---------------- host ----------------

extern "C" void kernel_launch(void* const* d_in, const int* in_sizes, int n_in,
                              void* d_out, int out_size, void* d_ws, size_t ws_size,
                              hipStream_t stream) {
  (void)in_sizes; (void)n_in; (void)out_size; (void)ws_size;
  const int* inputs = (const int*)d_in[0];
  const float* embed = (const float*)d_in[1];
  const float* lWih = (const float*)d_in[2];
  const float* lWhh = (const float*)d_in[3];
  const float* lbih = (const float*)d_in[4];
  const float* lbhh = (const float*)d_in[5];
  const float* rWih = (const float*)d_in[6];
  const float* rWhh = (const float*)d_in[7];
  const float* rbih = (const float*)d_in[8];
  const float* rbhh = (const float*)d_in[9];
  const float* aWih = (const float*)d_in[10];
  const float* aWhh = (const float*)d_in[11];
  const float* abih = (const float*)d_in[12];
  const float* abhh = (const float*)d_in[13];
  const float* Wc1 = (const float*)d_in[14];
  const float* Wc2 = (const float*)d_in[15];
  const float* vc  = (const float*)d_in[16];
  const float* Wb  = (const float*)d_in[17];
  const float* Wd  = (const float*)d_in[18];
  const float* vd  = (const float*)d_in[19];
  const float* Wm  = (const float*)d_in[20];
  const float* vmv = (const float*)d_in[21];
  const float* Wsw = (const float*)d_in[22];
  const float* vsv = (const float*)d_in[23];
  const float* Wp  = (const float*)d_in[24];
  const float* vp  = (const float*)d_in[25];
  const float* Wpred = (const float*)d_in[26];

  char* ws = (char*)d_ws;
  size_t off = 0;
  auto alloc = [&](size_t bytes) -> void* {
    void* p = ws + off;
    off += (bytes + 255) & ~(size_t)255;
    return p;
  };
  unsigned short* xhi = (unsigned short*)alloc((size_t)M * EP * 2);
  unsigned short* xlo = (unsigned short*)alloc((size_t)M * EP * 2);
  unsigned short* wpad = (unsigned short*)alloc((size_t)4 * H3 * EP * 2);
  unsigned short* Whh_b = (unsigned short*)alloc((size_t)6 * H3 * H * 2);
  unsigned short* aWih_b = (unsigned short*)alloc((size_t)2 * H3 * H12 * 2);
  unsigned short* Wc1_b = (unsigned short*)alloc((size_t)H * H2 * 2);
  unsigned short* Wc2_b = (unsigned short*)alloc((size_t)H * H2 * 2);
  unsigned short* Wm_b  = (unsigned short*)alloc((size_t)H * H2 * 2);
  unsigned short* Wp_b  = (unsigned short*)alloc((size_t)H * H2 * 2);
  unsigned short* Wb_b  = (unsigned short*)alloc((size_t)H2 * H2 * 2);
  char* region1 = (char*)alloc((size_t)4 * M * H3 * 4);
  float* pre_lr = (float*)region1;
  float* S      = (float*)region1;
  float* pre_a  = (float*)region1;
  float* S2 = (float*)alloc((size_t)2 * STY * 4);   // kh1 partials: [pts | ptd]
  float* hl_f = (float*)alloc((size_t)M * H2 * 4);
  float* hr_f = (float*)alloc((size_t)M * H2 * 4);
  unsigned short* hl_hi = (unsigned short*)alloc((size_t)M * H2 * 2);
  unsigned short* hl_lo = (unsigned short*)alloc((size_t)M * H2 * 2);
  unsigned short* hr_hi = (unsigned short*)alloc((size_t)M * H2 * 2);
  unsigned short* hr_lo = (unsigned short*)alloc((size_t)M * H2 * 2);
  float* Hc = (float*)alloc((size_t)M * H * 4);     // transposed [H][M]
  float* Rc = (float*)alloc((size_t)M * H * 4);
  float* Hm = (float*)alloc((size_t)M * H * 4);     // transposed [H][M]
  float* Rm = (float*)alloc((size_t)M * H * 4);
  float* Hp = (float*)alloc((size_t)M * H * 4);
  float* HB = (float*)alloc((size_t)M * H2 * 4);    // transposed [H2][M]
  unsigned short* agg_hi = (unsigned short*)alloc((size_t)M * H12 * 2);
  unsigned short* agg_lo = (unsigned short*)alloc((size_t)M * H12 * 2);
  float* ar_f = (float*)alloc((size_t)M * H2 * 4);
  unsigned short* ar_hi = (unsigned short*)alloc((size_t)M * H2 * 2);
  unsigned short* ar_lo = (unsigned short*)alloc((size_t)M * H2 * 2);
  float* Arc = (float*)alloc((size_t)M * H * 4);

  // 1. staging (flattened grid)
  StageArgs sa{};
  sa.cs[0] = lWhh;  sa.cd[0] = Whh_b;                 sa.cn[0] = 2 * H3 * H;
  sa.cs[1] = rWhh;  sa.cd[1] = Whh_b + 2 * H3 * H;    sa.cn[1] = 2 * H3 * H;
  sa.cs[2] = aWhh;  sa.cd[2] = Whh_b + 4 * H3 * H;    sa.cn[2] = 2 * H3 * H;
  sa.cs[3] = aWih;  sa.cd[3] = aWih_b;                sa.cn[3] = 2 * H3 * H12;
  sa.cs[4] = Wc1;   sa.cd[4] = Wc1_b;                 sa.cn[4] = H * H2;
  sa.cs[5] = Wc2;   sa.cd[5] = Wc2_b;                 sa.cn[5] = H * H2;
  sa.cs[6] = Wm;    sa.cd[6] = Wm_b;                  sa.cn[6] = H * H2;
  sa.cs[7] = Wp;    sa.cd[7] = Wp_b;                  sa.cn[7] = H * H2;
  sa.cs[8] = Wb;    sa.cd[8] = Wb_b;                  sa.cn[8] = H2 * H2;
  sa.idx = inputs; sa.emb = embed; sa.xhi = xhi; sa.xlo = xlo;
  sa.lW = lWih; sa.rW = rWih; sa.wpad = wpad;
  {
    int acc0 = 0;
    sa.bo[0] = 0;
    for (int s = 0; s < 9; ++s) { acc0 += (sa.cn[s] + 255) / 256; sa.bo[s + 1] = acc0; }
    acc0 += (M * EP + 255) / 256;       sa.bo[10] = acc0;
    acc0 += (4 * H3 * EP + 255) / 256;  sa.bo[11] = acc0;
  }
  k_stage<<<dim3(sa.bo[11]), dim3(256), 0, stream>>>(sa);

  // 2. input projections for l/r GRUs
  GemmBatch ga{};
  const float* biases[4] = { lbih, lbih + H3, rbih, rbih + H3 };
  for (int u = 0; u < 4; ++u)
    ga.d[u] = GemmDesc{ xhi, xlo, wpad + (size_t)u * H3 * EP, biases[u],
                        pre_lr + (size_t)u * M * H3, H3, EP, 0 };
  k_gemm<<<dim3(16, 6, 4), dim3(256), 0, stream>>>(ga);

  // 3. l/r recurrences (writes fp32 + hi/lo + agg hr-copy); 1 unit per block
  RecArgs r1{};
  r1.whh[0] = Whh_b;               r1.whh[1] = Whh_b + H3 * H;
  r1.whh[2] = Whh_b + 2 * H3 * H;  r1.whh[3] = Whh_b + 3 * H3 * H;
  for (int u = 0; u < 4; ++u) r1.pre[u] = pre_lr + (size_t)u * M * H3;
  r1.outf[0] = r1.outf[1] = hl_f; r1.outf[2] = r1.outf[3] = hr_f;
  r1.outhi[0] = r1.outhi[1] = hl_hi; r1.outhi[2] = r1.outhi[3] = hr_hi;
  r1.outlo[0] = r1.outlo[1] = hl_lo; r1.outlo[2] = r1.outlo[3] = hr_lo;
  r1.agghi[0] = r1.agghi[1] = nullptr; r1.agghi[2] = r1.agghi[3] = agg_hi;
  r1.agglo[0] = r1.agglo[1] = nullptr; r1.agglo[2] = r1.agglo[3] = agg_lo;
  r1.bhh[0] = lbhh; r1.bhh[1] = lbhh + H3; r1.bhh[2] = rbhh; r1.bhh[3] = rbhh + H3;
  r1.colOff[0] = 0; r1.colOff[1] = H; r1.colOff[2] = 0; r1.colOff[3] = H;
  r1.dir[0] = 0; r1.dir[1] = 1; r1.dir[2] = 0; r1.dir[3] = 1;
  k_gru<<<dim3(4), dim3(512), 0, stream>>>(r1);

  // 4. projection GEMMs (Hc/Hm/HB transposed for the j-streamed cmb path)
  GemmBatch gbB{};
  gbB.d[0] = GemmDesc{ hl_hi, hl_lo, Wc1_b, nullptr, Hc, H, H2, 1 };
  gbB.d[1] = GemmDesc{ hr_hi, hr_lo, Wc2_b, nullptr, Rc, H, H2, 0 };
  gbB.d[2] = GemmDesc{ hl_hi, hl_lo, Wm_b, nullptr, Hm, H, H2, 1 };
  gbB.d[3] = GemmDesc{ hr_hi, hr_lo, Wm_b, nullptr, Rm, H, H2, 0 };
  gbB.d[4] = GemmDesc{ hl_hi, hl_lo, Wb_b, nullptr, HB, H2, H2, 1 };
  gbB.d[5] = GemmDesc{ hl_hi, hl_lo, Wp_b, nullptr, Hp, H, H2, 0 };
  k_gemm<<<dim3(16, 4, 6), dim3(256), 0, stream>>>(gbB);

  // 5a. MFMA scores (pts/ptd halves)
  ScMMArgs sm{};
  sm.Xhi[0] = hl_hi; sm.Wt[0] = Wd;  sm.vt[0] = vd;  sm.So[0] = S + (size_t)2 * STY;
  sm.Xhi[1] = hr_hi; sm.Wt[1] = Wsw; sm.vt[1] = vsv; sm.So[1] = S + (size_t)0 * STY;
  sm.So2[0] = S2 + (size_t)STY;   // ptd kh1 partial
  sm.So2[1] = S2;                 // pts kh1 partial
  sm.Rf = hr_f;
  k_scmm<<<dim3(M, 4), dim3(256), 0, stream>>>(sm);

  // 5b. combined ptc/ptb/ptm scores (4 i-rows/block)
  ScCmbArgs scb{};
  scb.Hc = Hc; scb.Rc = Rc; scb.Hm = Hm; scb.Rm = Rm; scb.HB = HB;
  scb.hrf = hr_f; scb.vcf = vc; scb.vmf = vmv; scb.S = S;
  k_sccmb<<<dim3(256), dim3(256), 0, stream>>>(scb);

  // 6. softmax + weighted sums into agg
  k_wsum<<<dim3(32, 5, 4), dim3(256), 0, stream>>>(S, S2, hl_f, hr_f, agg_hi, agg_lo);

  // 7. agg GRU input projection
  GemmBatch gc{};
  gc.d[0] = GemmDesc{ agg_hi, agg_lo, aWih_b, abih, pre_a, H3, H12, 0 };
  gc.d[1] = GemmDesc{ agg_hi, agg_lo, aWih_b + (size_t)H3 * H12, abih + H3,
                      pre_a + (size_t)M * H3, H3, H12, 0 };
  k_gemm<<<dim3(16, 6, 2), dim3(256), 0, stream>>>(gc);

  // 8. agg recurrence (writes ar fp32 + hi/lo); 1 unit per block
  RecArgs r2{};
  r2.whh[0] = Whh_b + 4 * H3 * H; r2.whh[1] = Whh_b + 5 * H3 * H;
  r2.whh[2] = r2.whh[3] = Whh_b + 4 * H3 * H;
  r2.pre[0] = pre_a; r2.pre[1] = pre_a + (size_t)M * H3;
  r2.pre[2] = r2.pre[3] = pre_a;
  r2.outf[0] = r2.outf[1] = r2.outf[2] = r2.outf[3] = ar_f;
  r2.outhi[0] = r2.outhi[1] = r2.outhi[2] = r2.outhi[3] = ar_hi;
  r2.outlo[0] = r2.outlo[1] = r2.outlo[2] = r2.outlo[3] = ar_lo;
  for (int u = 0; u < 4; ++u) { r2.agghi[u] = nullptr; r2.agglo[u] = nullptr; }
  r2.bhh[0] = abhh; r2.bhh[1] = abhh + H3; r2.bhh[2] = r2.bhh[3] = abhh;
  r2.colOff[0] = 0; r2.colOff[1] = H; r2.colOff[2] = r2.colOff[3] = 0;
  r2.dir[0] = 0; r2.dir[1] = 1; r2.dir[2] = r2.dir[3] = 0;
  k_gru<<<dim3(2), dim3(512), 0, stream>>>(r2);

  // 9. Arc GEMM
  GemmBatch gd{};
  gd.d[0] = GemmDesc{ ar_hi, ar_lo, Wc1_b, nullptr, Arc, H, H2, 0 };
  k_gemm<<<dim3(16, 2, 1), dim3(256), 0, stream>>>(gd);

  // 10. fused tail
  k_tail<<<dim3(4), dim3(256), 0, stream>>>(Hp, hl_f, vp, Wc2, Arc, ar_f, vc, Wpred,
                                            (float*)d_out);
}